// Round 2
// baseline (1387.193 us; speedup 1.0000x reference)
//
#include <hip/hip_runtime.h>
#include <hip/hip_fp16.h>
#include <stdint.h>

// ---------------------------------------------------------------------------
// Seq2SeqARDiffusion on MI355X.
//   k_prep_xh : pack [x_hist|emb] fp16 inputs for LSTM0, layout [t][b][12 u32]
//   k_prep_w  : pack LSTM0/LSTM1/W2 weights to fp16 (+ bias sums)
//   k_lstm0   : persistent LSTM layer 0, 256 WGs x 512 thr, b128 LDS reads
//   k_lstm1   : persistent LSTM layer 1 -> enc_out, b128 LDS reads
//   k_diff    : persistent AR-diffusion, 1024 WGs x 64 thr (1 wave = 1 batch),
//               barrier-free (single-wave), DPP wave reduction
// ---------------------------------------------------------------------------

typedef __attribute__((ext_vector_type(2))) _Float16 half2_t;

#define DEV __device__ __forceinline__

DEV float fdot2(uint32_t a, uint32_t b, float c) {
#if __has_builtin(__builtin_amdgcn_fdot2)
  return __builtin_amdgcn_fdot2(__builtin_bit_cast(half2_t, a),
                                __builtin_bit_cast(half2_t, b), c, false);
#else
  half2_t ha = __builtin_bit_cast(half2_t, a);
  half2_t hb = __builtin_bit_cast(half2_t, b);
  return c + (float)ha.x * (float)hb.x + (float)ha.y * (float)hb.y;
#endif
}

DEV uint32_t pack2f(float a, float b) {
  __half ha = __float2half_rn(a), hb = __float2half_rn(b);
  return (uint32_t)__half_as_ushort(ha) | ((uint32_t)__half_as_ushort(hb) << 16);
}

DEV float sigm(float x) { return 1.0f / (1.0f + expf(-x)); }

// Full-wave (64-lane) sum via DPP adds (VALU-rate, no LDS pipe), result
// broadcast to all lanes via readlane. rocPRIM-style sequence.
DEV float wave_sum64(float v) {
  int x;
  x = __builtin_amdgcn_update_dpp(0, __builtin_bit_cast(int, v), 0x111, 0xf, 0xf, true); // row_shr:1
  v += __builtin_bit_cast(float, x);
  x = __builtin_amdgcn_update_dpp(0, __builtin_bit_cast(int, v), 0x112, 0xf, 0xf, true); // row_shr:2
  v += __builtin_bit_cast(float, x);
  x = __builtin_amdgcn_update_dpp(0, __builtin_bit_cast(int, v), 0x114, 0xf, 0xf, true); // row_shr:4
  v += __builtin_bit_cast(float, x);
  x = __builtin_amdgcn_update_dpp(0, __builtin_bit_cast(int, v), 0x118, 0xf, 0xf, true); // row_shr:8
  v += __builtin_bit_cast(float, x);
  x = __builtin_amdgcn_update_dpp(0, __builtin_bit_cast(int, v), 0x142, 0xa, 0xf, true); // row_bcast15 -> rows 1,3
  v += __builtin_bit_cast(float, x);
  x = __builtin_amdgcn_update_dpp(0, __builtin_bit_cast(int, v), 0x143, 0xc, 0xf, true); // row_bcast31 -> rows 2,3
  v += __builtin_bit_cast(float, x);
  return __builtin_bit_cast(float, __builtin_amdgcn_readlane(__builtin_bit_cast(int, v), 63));
}

// ---------------- workspace layout (bytes) ----------------
static constexpr size_t OFF_XH  = 0;                 // 96*1024*12 u32 = 4,718,592
static constexpr size_t OFF_W0  = 4718592;           // 512*80 u32 = 163,840
static constexpr size_t OFF_BS0 = 4882432;           // 512 f32
static constexpr size_t OFF_W1L = 4884480;           // 512*128 u32 = 262,144
static constexpr size_t OFF_BS1 = 5146624;           // 512 f32
static constexpr size_t OFF_W2P = 5148672;           // 128*64 u32 = 32,768
static constexpr size_t OFF_ENC = 5181440;           // 1024*128 f32 = 524,288
static constexpr size_t OFF_YS0 = 5705728;           // 96*1024*128 half = 25,165,824
// total ~30.9 MB

// ---------------- prep: pack [x_hist | emb] as fp16 pairs ----------------
__global__ void k_prep_xh(const float* __restrict__ xh, const int* __restrict__ tix,
                          const float* __restrict__ temb, uint32_t* __restrict__ out) {
  int idx = blockIdx.x * 256 + threadIdx.x;          // 96*1024*12 total
  if (idx >= 96 * 1024 * 12) return;
  int m = idx % 12;
  int tb = idx / 12;
  int b = tb & 1023, t = tb >> 10;
  int k0 = 2 * m, k1 = k0 + 1;
  float v0 = (k0 < 8) ? xh[(b * 96 + t) * 8 + k0] : temb[tix[b] * 16 + (k0 - 8)];
  float v1 = (k1 < 8) ? xh[(b * 96 + t) * 8 + k1] : temb[tix[b] * 16 + (k1 - 8)];
  out[idx] = pack2f(v0, v1);
}

// ---------------- prep: pack weights fp16 ----------------
// W0 row (80 u32): halfs = [x 0:24 | h 0:128 | pad 0,0,...] -> u32 m holds halfs 2m,2m+1
__global__ void k_prep_w(const float* __restrict__ Wih0, const float* __restrict__ Whh0,
                         const float* __restrict__ bih0, const float* __restrict__ bhh0,
                         const float* __restrict__ Wih1, const float* __restrict__ Whh1,
                         const float* __restrict__ bih1, const float* __restrict__ bhh1,
                         const float* __restrict__ W2,
                         uint32_t* __restrict__ w0p, uint32_t* __restrict__ w1p,
                         uint32_t* __restrict__ w2p, float* __restrict__ bs0,
                         float* __restrict__ bs1) {
  int idx = blockIdx.x * 256 + threadIdx.x;
  if (idx < 40960) {                       // W0: 512 x 80 u32
    int g = idx / 80, m = idx % 80;
    int k0 = 2 * m, k1 = k0 + 1;
    float a = (k0 < 24) ? Wih0[g * 24 + k0] : ((k0 - 24 < 128) ? Whh0[g * 128 + k0 - 24] : 0.f);
    float b = (k1 < 24) ? Wih0[g * 24 + k1] : ((k1 - 24 < 128) ? Whh0[g * 128 + k1 - 24] : 0.f);
    w0p[idx] = pack2f(a, b);
  } else if (idx < 106496) {               // W1L: rows [Wih1 | Whh1], 512 x 128 u32
    int i = idx - 40960;
    int g = i >> 7, m = i & 127;
    int k0 = 2 * m, k1 = k0 + 1;
    float a = (k0 < 128) ? Wih1[g * 128 + k0] : Whh1[g * 128 + k0 - 128];
    float b = (k1 < 128) ? Wih1[g * 128 + k1] : Whh1[g * 128 + k1 - 128];
    w1p[i] = pack2f(a, b);
  } else if (idx < 114688) {               // W2: 128 x 64 u32 (row-major pairs)
    int i = idx - 106496;
    w2p[i] = pack2f(W2[2 * i], W2[2 * i + 1]);
  } else if (idx < 115200) {
    int i = idx - 114688;
    bs0[i] = bih0[i] + bhh0[i];
  } else if (idx < 115712) {
    int i = idx - 115200;
    bs1[i] = bih1[i] + bhh1[i];
  }
}

// ---------------- LSTM layer 0 (persistent; 4 batch/WG) ----------------
__global__ __launch_bounds__(512) void k_lstm0(const uint32_t* __restrict__ xh16,
                                               const uint32_t* __restrict__ w0p,
                                               const float* __restrict__ bs0,
                                               __half* __restrict__ ys0) {
  __shared__ __align__(16) uint32_t in_u[4][80];  // per b: [x(24)|h(128)|pad] halfs
  __shared__ float4 part[128][2][2];              // [j][bh][bi] partial gates from kh=1
  const int tid = threadIdx.x;
  const int j = tid & 127, kh = (tid >> 7) & 1, bh = tid >> 8;
  const int bbase = blockIdx.x * 4;

  uint4 wreg[4][10];
#pragma unroll
  for (int q = 0; q < 4; q++) {
    const uint4* src = (const uint4*)(w0p + (j + 128 * q) * 80 + kh * 40);
#pragma unroll
    for (int m = 0; m < 10; m++) wreg[q][m] = src[m];
  }
  float bsv[4] = {0.f, 0.f, 0.f, 0.f};
  if (kh == 0) {
#pragma unroll
    for (int q = 0; q < 4; q++) bsv[q] = bs0[j + 128 * q];
  }
  for (int z = tid; z < 320; z += 512) {
    int bb = z / 80, m = z % 80;
    if (m >= 12) in_u[bb][m] = 0u;   // zero h region + pads
  }
  float cst[2] = {0.f, 0.f};

  for (int t = 0; t < 96; t++) {
    if (tid >= 128 && tid < 176) {   // stage x_t (48 u32)
      int e = tid - 128;
      int bl = e / 12, m = e % 12;
      in_u[bl][m] = xh16[(t * 1024 + bbase + bl) * 12 + m];
    }
    __syncthreads();
    float acc[4][2];
#pragma unroll
    for (int q = 0; q < 4; q++) { acc[q][0] = 0.f; acc[q][1] = 0.f; }
#pragma unroll
    for (int bi = 0; bi < 2; bi++) {
      const uint4* iu = (const uint4*)&in_u[bh * 2 + bi][kh * 40];
#pragma unroll
      for (int m = 0; m < 10; m++) {
        uint4 u = iu[m];
#pragma unroll
        for (int q = 0; q < 4; q++) {
          acc[q][bi] = fdot2(wreg[q][m].x, u.x, acc[q][bi]);
          acc[q][bi] = fdot2(wreg[q][m].y, u.y, acc[q][bi]);
          acc[q][bi] = fdot2(wreg[q][m].z, u.z, acc[q][bi]);
          acc[q][bi] = fdot2(wreg[q][m].w, u.w, acc[q][bi]);
        }
      }
    }
    if (kh == 1) {
      part[j][bh][0] = make_float4(acc[0][0], acc[1][0], acc[2][0], acc[3][0]);
      part[j][bh][1] = make_float4(acc[0][1], acc[1][1], acc[2][1], acc[3][1]);
    }
    __syncthreads();
    if (kh == 0) {
#pragma unroll
      for (int bi = 0; bi < 2; bi++) {
        int b = bh * 2 + bi;
        float4 p = part[j][bh][bi];
        float gi = acc[0][bi] + p.x + bsv[0];
        float gf = acc[1][bi] + p.y + bsv[1];
        float gg = acc[2][bi] + p.z + bsv[2];
        float go = acc[3][bi] + p.w + bsv[3];
        float c = sigm(gf) * cst[bi] + sigm(gi) * tanhf(gg);
        cst[bi] = c;
        float h = sigm(go) * tanhf(c);
        __half hh = __float2half_rn(h);
        ((__half*)&in_u[b][0])[24 + j] = hh;
        ys0[(t * 1024 + bbase + b) * 128 + j] = hh;
      }
    }
  }
}

// ---------------- LSTM layer 1 (persistent; 4 batch/WG) ----------------
__global__ __launch_bounds__(512) void k_lstm1(const uint32_t* __restrict__ ys0u,
                                               const uint32_t* __restrict__ w1p,
                                               const float* __restrict__ bs1,
                                               float* __restrict__ enc) {
  __shared__ __align__(16) uint32_t in_u[4][128];  // per b: [ys0_t(128)|h(128)] halfs
  __shared__ float4 part[3][128][4];
  const int tid = threadIdx.x;
  const int j = tid & 127, kq = tid >> 7;
  const int bbase = blockIdx.x * 4;

  uint4 wreg[4][8];
#pragma unroll
  for (int q = 0; q < 4; q++) {
    const uint4* src = (const uint4*)(w1p + (j + 128 * q) * 128 + kq * 32);
#pragma unroll
    for (int m = 0; m < 8; m++) wreg[q][m] = src[m];
  }
  float bsv[4] = {0.f, 0.f, 0.f, 0.f};
  float cst[4] = {0.f, 0.f, 0.f, 0.f};
  if (kq == 0) {
#pragma unroll
    for (int q = 0; q < 4; q++) bsv[q] = bs1[j + 128 * q];
  }
  for (int z = tid; z < 256; z += 512) {
    int bb = z >> 6, m = z & 63;
    in_u[bb][64 + m] = 0u;
  }

  for (int t = 0; t < 96; t++) {
    if (tid >= 256) {
      int e = tid - 256;
      int bl = e >> 6, m = e & 63;
      in_u[bl][m] = ys0u[(t * 1024 + bbase + bl) * 64 + m];
    }
    __syncthreads();
    float acc[4][4];
#pragma unroll
    for (int q = 0; q < 4; q++)
#pragma unroll
      for (int b = 0; b < 4; b++) acc[q][b] = 0.f;
#pragma unroll
    for (int b = 0; b < 4; b++) {
      const uint4* iu = (const uint4*)&in_u[b][kq * 32];
#pragma unroll
      for (int m = 0; m < 8; m++) {
        uint4 u = iu[m];
#pragma unroll
        for (int q = 0; q < 4; q++) {
          acc[q][b] = fdot2(wreg[q][m].x, u.x, acc[q][b]);
          acc[q][b] = fdot2(wreg[q][m].y, u.y, acc[q][b]);
          acc[q][b] = fdot2(wreg[q][m].z, u.z, acc[q][b]);
          acc[q][b] = fdot2(wreg[q][m].w, u.w, acc[q][b]);
        }
      }
    }
    if (kq > 0) {
#pragma unroll
      for (int b = 0; b < 4; b++)
        part[kq - 1][j][b] = make_float4(acc[0][b], acc[1][b], acc[2][b], acc[3][b]);
    }
    __syncthreads();
    if (kq == 0) {
#pragma unroll
      for (int b = 0; b < 4; b++) {
        float4 p0 = part[0][j][b], p1 = part[1][j][b], p2 = part[2][j][b];
        float gi = acc[0][b] + p0.x + p1.x + p2.x + bsv[0];
        float gf = acc[1][b] + p0.y + p1.y + p2.y + bsv[1];
        float gg = acc[2][b] + p0.z + p1.z + p2.z + bsv[2];
        float go = acc[3][b] + p0.w + p1.w + p2.w + bsv[3];
        float c = sigm(gf) * cst[b] + sigm(gi) * tanhf(gg);
        cst[b] = c;
        float h = sigm(go) * tanhf(c);
        ((__half*)&in_u[b][0])[128 + j] = __float2half_rn(h);
        if (t == 95) enc[(bbase + b) * 128 + j] = h;
      }
    }
  }
}

// ---------------- AR diffusion: 1 wave per batch, barrier-free ----------------
// lane l owns MLP-hidden rows r0=2l, r1=2l+1.
// W1 cols: [0:128) enc | [128:134) exo | [134:150) emb | 150 prev_y | 151 y |
//          [152:168) t_e | [168:184) h_e
__global__ __launch_bounds__(64, 1) void k_diff(
    const float* __restrict__ xfut, const float* __restrict__ y0,
    const int* __restrict__ tix, const float* __restrict__ noise,
    const float* __restrict__ temb, const float* __restrict__ W1,
    const float* __restrict__ b1, const float* __restrict__ b2,
    const float* __restrict__ W3, const float* __restrict__ b3,
    const uint32_t* __restrict__ w2p, const float* __restrict__ enc,
    float* __restrict__ out) {
  __shared__ float teL[100][16];
  __shared__ float2 ccL[100];                      // (csub, cdiv)
  __shared__ __align__(16) float encL[128];
  __shared__ __align__(16) uint32_t tprojU[100 * 64];  // [t][lane] = (tproj[2l],tproj[2l+1])
  __shared__ __align__(16) uint32_t h1u[64];
  const int l = threadIdx.x;
  const int b = blockIdx.x;
  const int r0 = 2 * l, r1 = r0 + 1;
  const float* w1r0 = W1 + r0 * 184;
  const float* w1r1 = W1 + r1 * 184;

  // sinusoidal table
  for (int p = l; p < 1600; p += 64) {
    int tt = p >> 4, i = p & 15;
    float f = expf(-logf(10000.f) * (float)(i & 7) / 8.f);
    float a = (float)tt * f;
    teL[tt][i] = (i < 8) ? cosf(a) : sinf(a);
  }
  // diffusion coefficients
  for (int q = l; q < 100; q += 64) {
    float ab = 1.f, beta = 0.f;
    for (int i = 0; i <= q; i++) {
      beta = 1e-4f + (0.02f - 1e-4f) * (float)i / 99.f;
      ab *= (1.f - beta);
    }
    float cs, cd;
    if (q == 0) { cs = sqrtf(1.f - ab); cd = 1.f / (sqrtf(ab) + 1e-8f); }
    else { cs = beta / (sqrtf(1.f - ab) + 1e-8f); cd = 1.f / (sqrtf(1.f - beta) + 1e-8f); }
    ccL[q] = make_float2(cs, cd);
  }
  encL[l] = enc[b * 128 + l];
  encL[64 + l] = enc[b * 128 + 64 + l];
  __syncthreads();

  // tproj[t][r] = W1_te(row r) . te[t]
  {
    float wt0[16], wt1[16];
#pragma unroll
    for (int i = 0; i < 16; i++) { wt0[i] = w1r0[152 + i]; wt1[i] = w1r1[152 + i]; }
    for (int tt = 0; tt < 100; tt++) {
      float s0 = 0.f, s1 = 0.f;
#pragma unroll
      for (int i = 0; i < 16; i++) { s0 += wt0[i] * teL[tt][i]; s1 += wt1[i] * teL[tt][i]; }
      tprojU[tt * 64 + l] = pack2f(s0, s1);
    }
  }
  // enc & emb dot (constant over AR steps)
  float encd0 = 0.f, encd1 = 0.f;
  {
    const float4* ev = (const float4*)encL;
    const float4* a4 = (const float4*)w1r0;
    const float4* c4 = (const float4*)w1r1;
#pragma unroll 8
    for (int kk = 0; kk < 32; kk++) {
      float4 e = ev[kk], a = a4[kk], c = c4[kk];
      encd0 += a.x * e.x + a.y * e.y + a.z * e.z + a.w * e.w;
      encd1 += c.x * e.x + c.y * e.y + c.z * e.z + c.w * e.w;
    }
  }
  float embd0 = 0.f, embd1 = 0.f;
  {
    const float* er = temb + tix[b] * 16;
#pragma unroll
    for (int i = 0; i < 16; i++) {
      float v = er[i];
      embd0 += w1r0[134 + i] * v;
      embd1 += w1r1[134 + i] * v;
    }
  }
  // W2 rows in VGPRs
  uint32_t w2a[64], w2b[64];
#pragma unroll
  for (int m = 0; m < 64; m++) { w2a[m] = w2p[r0 * 64 + m]; w2b[m] = w2p[r1 * 64 + m]; }
  const float w1y0 = w1r0[151], w1y1 = w1r1[151];
  const float w150a = w1r0[150], w150b = w1r1[150];
  const float b2a = b2[r0], b2b = b2[r1];
  const float w3a = W3[r0], w3b = W3[r1];
  const float base0 = b1[r0] + encd0 + embd0;
  const float base1 = b1[r1] + encd1 + embd1;
  const float b3v = b3[0];
  float prev_y = y0[b];
  __syncthreads();

  for (int s = 0; s < 8; s++) {
    float e0 = fmaf(w150a, prev_y, base0);
    float e1 = fmaf(w150b, prev_y, base1);
#pragma unroll
    for (int i = 0; i < 6; i++) {
      float xv = xfut[(b * 8 + s) * 6 + i];
      e0 = fmaf(w1r0[128 + i], xv, e0);
      e1 = fmaf(w1r1[128 + i], xv, e1);
    }
#pragma unroll
    for (int i = 0; i < 16; i++) {
      float tv = teL[s][i];
      e0 = fmaf(w1r0[168 + i], tv, e0);
      e1 = fmaf(w1r1[168 + i], tv, e1);
    }
    float y = noise[s * 1024 + b];
    uint32_t tp = tprojU[99 * 64 + l];
    for (int t = 99; t >= 0; t--) {
      half2_t th = __builtin_bit_cast(half2_t, tp);
      float h0 = fmaxf(fmaf(y, w1y0, e0 + (float)th.x), 0.f);
      float h1 = fmaxf(fmaf(y, w1y1, e1 + (float)th.y), 0.f);
      h1u[l] = pack2f(h0, h1);
      __syncthreads();                      // single wave: waitcnt only
      tp = tprojU[(t > 0 ? t - 1 : 0) * 64 + l];   // prefetch next step's pair
      float2 cc = ccL[t];
      float a0 = 0.f, a1 = 0.f, a2 = 0.f, a3 = 0.f;
      const uint4* hv = (const uint4*)h1u;
#pragma unroll
      for (int mm = 0; mm < 16; mm++) {     // broadcast b128 reads, 4 acc chains
        uint4 u = hv[mm];
        a0 = fdot2(w2a[4 * mm + 0], u.x, a0);
        a1 = fdot2(w2a[4 * mm + 1], u.y, a1);
        a0 = fdot2(w2a[4 * mm + 2], u.z, a0);
        a1 = fdot2(w2a[4 * mm + 3], u.w, a1);
        a2 = fdot2(w2b[4 * mm + 0], u.x, a2);
        a3 = fdot2(w2b[4 * mm + 1], u.y, a3);
        a2 = fdot2(w2b[4 * mm + 2], u.z, a2);
        a3 = fdot2(w2b[4 * mm + 3], u.w, a3);
      }
      float h2a = fmaxf(a0 + a1 + b2a, 0.f);
      float h2b = fmaxf(a2 + a3 + b2b, 0.f);
      float eps = wave_sum64(fmaf(w3a, h2a, w3b * h2b)) + b3v;
      y = (y - cc.x * eps) * cc.y;
    }
    if (l == 0) out[b * 8 + s] = y;
    prev_y = y;
  }
}

// ---------------------------------------------------------------------------
extern "C" void kernel_launch(void* const* d_in, const int* in_sizes, int n_in,
                              void* d_out, int out_size, void* d_ws, size_t ws_size,
                              hipStream_t stream) {
  const float* x_hist    = (const float*)d_in[0];
  const float* x_future  = (const float*)d_in[1];
  const float* y0        = (const float*)d_in[2];
  const int*   turb_idx  = (const int*)d_in[3];
  const float* init_noise = (const float*)d_in[5];
  const float* turb_emb  = (const float*)d_in[6];
  const float* W_ih0     = (const float*)d_in[7];
  const float* W_hh0     = (const float*)d_in[8];
  const float* b_ih0     = (const float*)d_in[9];
  const float* b_hh0     = (const float*)d_in[10];
  const float* W_ih1     = (const float*)d_in[11];
  const float* W_hh1     = (const float*)d_in[12];
  const float* b_ih1     = (const float*)d_in[13];
  const float* b_hh1     = (const float*)d_in[14];
  const float* W1        = (const float*)d_in[15];
  const float* b1        = (const float*)d_in[16];
  const float* W2        = (const float*)d_in[17];
  const float* b2        = (const float*)d_in[18];
  const float* W3        = (const float*)d_in[19];
  const float* b3        = (const float*)d_in[20];

  char* ws = (char*)d_ws;
  uint32_t* xh16 = (uint32_t*)(ws + OFF_XH);
  uint32_t* w0p  = (uint32_t*)(ws + OFF_W0);
  float*    bs0  = (float*)(ws + OFF_BS0);
  uint32_t* w1p  = (uint32_t*)(ws + OFF_W1L);
  float*    bs1  = (float*)(ws + OFF_BS1);
  uint32_t* w2p  = (uint32_t*)(ws + OFF_W2P);
  float*    encf = (float*)(ws + OFF_ENC);
  __half*   ys0h = (__half*)(ws + OFF_YS0);

  k_prep_xh<<<4608, 256, 0, stream>>>(x_hist, turb_idx, turb_emb, xh16);
  k_prep_w<<<452, 256, 0, stream>>>(W_ih0, W_hh0, b_ih0, b_hh0,
                                    W_ih1, W_hh1, b_ih1, b_hh1,
                                    W2, w0p, w1p, w2p, bs0, bs1);
  k_lstm0<<<256, 512, 0, stream>>>(xh16, w0p, bs0, ys0h);
  k_lstm1<<<256, 512, 0, stream>>>((const uint32_t*)ys0h, w1p, bs1, encf);
  k_diff<<<1024, 64, 0, stream>>>(x_future, y0, turb_idx, init_noise, turb_emb,
                                  W1, b1, b2, W3, b3, w2p, encf, (float*)d_out);
}

// Round 3
// 1173.983 us; speedup vs baseline: 1.1816x; 1.1816x over previous
//
#include <hip/hip_runtime.h>
#include <hip/hip_fp16.h>
#include <stdint.h>

// ---------------------------------------------------------------------------
// Seq2SeqARDiffusion on MI355X.
//   k_prep_xh : pack [x_hist|emb] fp16 inputs for LSTM0, layout [t][b][12 u32]
//   k_prep_w  : pack LSTM0/LSTM1/W2 weights to fp16 (+ bias sums)
//   k_lstm0   : persistent LSTM layer 0, 256 WGs x 512 thr
//   k_lstm1   : persistent LSTM layer 1 -> enc_out
//   k_diff    : persistent AR-diffusion, 64 WGs x 256 thr (4 waves, 16 batch/WG),
//               MFMA 16x16x32_f16 for the 128x128 layer, 1 barrier/step
// ---------------------------------------------------------------------------

typedef __attribute__((ext_vector_type(2))) _Float16 half2_t;
typedef __attribute__((ext_vector_type(8))) _Float16 v8h;
typedef __attribute__((ext_vector_type(4))) float v4f;

#define DEV __device__ __forceinline__

DEV float fdot2(uint32_t a, uint32_t b, float c) {
#if __has_builtin(__builtin_amdgcn_fdot2)
  return __builtin_amdgcn_fdot2(__builtin_bit_cast(half2_t, a),
                                __builtin_bit_cast(half2_t, b), c, false);
#else
  half2_t ha = __builtin_bit_cast(half2_t, a);
  half2_t hb = __builtin_bit_cast(half2_t, b);
  return c + (float)ha.x * (float)hb.x + (float)ha.y * (float)hb.y;
#endif
}

DEV uint32_t pack2f(float a, float b) {
  __half ha = __float2half_rn(a), hb = __float2half_rn(b);
  return (uint32_t)__half_as_ushort(ha) | ((uint32_t)__half_as_ushort(hb) << 16);
}

DEV float2 up2(uint32_t u) {
  half2_t h = __builtin_bit_cast(half2_t, u);
  return make_float2((float)h.x, (float)h.y);
}

DEV float sigm(float x) { return 1.0f / (1.0f + expf(-x)); }

// h1 pair = relu(base + tproj + w1y*y), all packed fp16
DEV uint32_t pk_h1(uint32_t b, uint32_t t, uint32_t wy, uint32_t yP) {
  half2_t hb = __builtin_bit_cast(half2_t, b);
  half2_t ht = __builtin_bit_cast(half2_t, t);
  half2_t hw = __builtin_bit_cast(half2_t, wy);
  half2_t hy = __builtin_bit_cast(half2_t, yP);
  half2_t r = hb + ht + hw * hy;
  half2_t z = {(_Float16)0.f, (_Float16)0.f};
#if __has_builtin(__builtin_elementwise_max)
  r = __builtin_elementwise_max(r, z);
#else
  uint32_t u = __builtin_bit_cast(uint32_t, r);
  uint32_t mask = ((u >> 15) & 1u) * 0xFFFFu | ((u >> 31) & 1u) * 0xFFFF0000u;
  r = __builtin_bit_cast(half2_t, u & ~mask);
#endif
  return __builtin_bit_cast(uint32_t, r);
}

// sum over each 16-lane row; lane (l&15)==15 of each row holds the row sum
DEV float rowsum16(float v) {
  int x;
  x = __builtin_amdgcn_update_dpp(0, __builtin_bit_cast(int, v), 0x111, 0xf, 0xf, true);
  v += __builtin_bit_cast(float, x);
  x = __builtin_amdgcn_update_dpp(0, __builtin_bit_cast(int, v), 0x112, 0xf, 0xf, true);
  v += __builtin_bit_cast(float, x);
  x = __builtin_amdgcn_update_dpp(0, __builtin_bit_cast(int, v), 0x114, 0xf, 0xf, true);
  v += __builtin_bit_cast(float, x);
  x = __builtin_amdgcn_update_dpp(0, __builtin_bit_cast(int, v), 0x118, 0xf, 0xf, true);
  v += __builtin_bit_cast(float, x);
  return v;
}

// ---------------- workspace layout (bytes) ----------------
static constexpr size_t OFF_XH  = 0;                 // 96*1024*12 u32 = 4,718,592
static constexpr size_t OFF_W0  = 4718592;           // 512*80 u32 = 163,840
static constexpr size_t OFF_BS0 = 4882432;           // 512 f32
static constexpr size_t OFF_W1L = 4884480;           // 512*128 u32 = 262,144
static constexpr size_t OFF_BS1 = 5146624;           // 512 f32
static constexpr size_t OFF_W2P = 5148672;           // 128*64 u32 = 32,768
static constexpr size_t OFF_ENC = 5181440;           // 1024*128 f32 = 524,288
static constexpr size_t OFF_YS0 = 5705728;           // 96*1024*128 half = 25,165,824
// total ~30.9 MB

// ---------------- prep: pack [x_hist | emb] as fp16 pairs ----------------
__global__ void k_prep_xh(const float* __restrict__ xh, const int* __restrict__ tix,
                          const float* __restrict__ temb, uint32_t* __restrict__ out) {
  int idx = blockIdx.x * 256 + threadIdx.x;          // 96*1024*12 total
  if (idx >= 96 * 1024 * 12) return;
  int m = idx % 12;
  int tb = idx / 12;
  int b = tb & 1023, t = tb >> 10;
  int k0 = 2 * m, k1 = k0 + 1;
  float v0 = (k0 < 8) ? xh[(b * 96 + t) * 8 + k0] : temb[tix[b] * 16 + (k0 - 8)];
  float v1 = (k1 < 8) ? xh[(b * 96 + t) * 8 + k1] : temb[tix[b] * 16 + (k1 - 8)];
  out[idx] = pack2f(v0, v1);
}

// ---------------- prep: pack weights fp16 ----------------
__global__ void k_prep_w(const float* __restrict__ Wih0, const float* __restrict__ Whh0,
                         const float* __restrict__ bih0, const float* __restrict__ bhh0,
                         const float* __restrict__ Wih1, const float* __restrict__ Whh1,
                         const float* __restrict__ bih1, const float* __restrict__ bhh1,
                         const float* __restrict__ W2,
                         uint32_t* __restrict__ w0p, uint32_t* __restrict__ w1p,
                         uint32_t* __restrict__ w2p, float* __restrict__ bs0,
                         float* __restrict__ bs1) {
  int idx = blockIdx.x * 256 + threadIdx.x;
  if (idx < 40960) {                       // W0: 512 x 80 u32
    int g = idx / 80, m = idx % 80;
    int k0 = 2 * m, k1 = k0 + 1;
    float a = (k0 < 24) ? Wih0[g * 24 + k0] : ((k0 - 24 < 128) ? Whh0[g * 128 + k0 - 24] : 0.f);
    float b = (k1 < 24) ? Wih0[g * 24 + k1] : ((k1 - 24 < 128) ? Whh0[g * 128 + k1 - 24] : 0.f);
    w0p[idx] = pack2f(a, b);
  } else if (idx < 106496) {               // W1L: rows [Wih1 | Whh1], 512 x 128 u32
    int i = idx - 40960;
    int g = i >> 7, m = i & 127;
    int k0 = 2 * m, k1 = k0 + 1;
    float a = (k0 < 128) ? Wih1[g * 128 + k0] : Whh1[g * 128 + k0 - 128];
    float b = (k1 < 128) ? Wih1[g * 128 + k1] : Whh1[g * 128 + k1 - 128];
    w1p[i] = pack2f(a, b);
  } else if (idx < 114688) {               // W2: 128 x 64 u32 (row-major pairs)
    int i = idx - 106496;
    w2p[i] = pack2f(W2[2 * i], W2[2 * i + 1]);
  } else if (idx < 115200) {
    int i = idx - 114688;
    bs0[i] = bih0[i] + bhh0[i];
  } else if (idx < 115712) {
    int i = idx - 115200;
    bs1[i] = bih1[i] + bhh1[i];
  }
}

// ---------------- LSTM layer 0 (persistent; 4 batch/WG) ----------------
__global__ __launch_bounds__(512) void k_lstm0(const uint32_t* __restrict__ xh16,
                                               const uint32_t* __restrict__ w0p,
                                               const float* __restrict__ bs0,
                                               __half* __restrict__ ys0) {
  __shared__ __align__(16) uint32_t in_u[4][80];  // per b: [x(24)|h(128)|pad] halfs
  __shared__ float4 part[128][2][2];              // [j][bh][bi] partial gates from kh=1
  const int tid = threadIdx.x;
  const int j = tid & 127, kh = (tid >> 7) & 1, bh = tid >> 8;
  const int bbase = blockIdx.x * 4;

  uint4 wreg[4][10];
#pragma unroll
  for (int q = 0; q < 4; q++) {
    const uint4* src = (const uint4*)(w0p + (j + 128 * q) * 80 + kh * 40);
#pragma unroll
    for (int m = 0; m < 10; m++) wreg[q][m] = src[m];
  }
  float bsv[4] = {0.f, 0.f, 0.f, 0.f};
  if (kh == 0) {
#pragma unroll
    for (int q = 0; q < 4; q++) bsv[q] = bs0[j + 128 * q];
  }
  for (int z = tid; z < 320; z += 512) {
    int bb = z / 80, m = z % 80;
    if (m >= 12) in_u[bb][m] = 0u;   // zero h region + pads
  }
  float cst[2] = {0.f, 0.f};

  for (int t = 0; t < 96; t++) {
    if (tid >= 128 && tid < 176) {   // stage x_t (48 u32)
      int e = tid - 128;
      int bl = e / 12, m = e % 12;
      in_u[bl][m] = xh16[(t * 1024 + bbase + bl) * 12 + m];
    }
    __syncthreads();
    float acc[4][2];
#pragma unroll
    for (int q = 0; q < 4; q++) { acc[q][0] = 0.f; acc[q][1] = 0.f; }
#pragma unroll
    for (int bi = 0; bi < 2; bi++) {
      const uint4* iu = (const uint4*)&in_u[bh * 2 + bi][kh * 40];
#pragma unroll
      for (int m = 0; m < 10; m++) {
        uint4 u = iu[m];
#pragma unroll
        for (int q = 0; q < 4; q++) {
          acc[q][bi] = fdot2(wreg[q][m].x, u.x, acc[q][bi]);
          acc[q][bi] = fdot2(wreg[q][m].y, u.y, acc[q][bi]);
          acc[q][bi] = fdot2(wreg[q][m].z, u.z, acc[q][bi]);
          acc[q][bi] = fdot2(wreg[q][m].w, u.w, acc[q][bi]);
        }
      }
    }
    if (kh == 1) {
      part[j][bh][0] = make_float4(acc[0][0], acc[1][0], acc[2][0], acc[3][0]);
      part[j][bh][1] = make_float4(acc[0][1], acc[1][1], acc[2][1], acc[3][1]);
    }
    __syncthreads();
    if (kh == 0) {
#pragma unroll
      for (int bi = 0; bi < 2; bi++) {
        int b = bh * 2 + bi;
        float4 p = part[j][bh][bi];
        float gi = acc[0][bi] + p.x + bsv[0];
        float gf = acc[1][bi] + p.y + bsv[1];
        float gg = acc[2][bi] + p.z + bsv[2];
        float go = acc[3][bi] + p.w + bsv[3];
        float c = sigm(gf) * cst[bi] + sigm(gi) * tanhf(gg);
        cst[bi] = c;
        float h = sigm(go) * tanhf(c);
        __half hh = __float2half_rn(h);
        ((__half*)&in_u[b][0])[24 + j] = hh;
        ys0[(t * 1024 + bbase + b) * 128 + j] = hh;
      }
    }
  }
}

// ---------------- LSTM layer 1 (persistent; 4 batch/WG) ----------------
__global__ __launch_bounds__(512) void k_lstm1(const uint32_t* __restrict__ ys0u,
                                               const uint32_t* __restrict__ w1p,
                                               const float* __restrict__ bs1,
                                               float* __restrict__ enc) {
  __shared__ __align__(16) uint32_t in_u[4][128];  // per b: [ys0_t(128)|h(128)] halfs
  __shared__ float4 part[3][128][4];
  const int tid = threadIdx.x;
  const int j = tid & 127, kq = tid >> 7;
  const int bbase = blockIdx.x * 4;

  uint4 wreg[4][8];
#pragma unroll
  for (int q = 0; q < 4; q++) {
    const uint4* src = (const uint4*)(w1p + (j + 128 * q) * 128 + kq * 32);
#pragma unroll
    for (int m = 0; m < 8; m++) wreg[q][m] = src[m];
  }
  float bsv[4] = {0.f, 0.f, 0.f, 0.f};
  float cst[4] = {0.f, 0.f, 0.f, 0.f};
  if (kq == 0) {
#pragma unroll
    for (int q = 0; q < 4; q++) bsv[q] = bs1[j + 128 * q];
  }
  for (int z = tid; z < 256; z += 512) {
    int bb = z >> 6, m = z & 63;
    in_u[bb][64 + m] = 0u;
  }

  for (int t = 0; t < 96; t++) {
    if (tid >= 256) {
      int e = tid - 256;
      int bl = e >> 6, m = e & 63;
      in_u[bl][m] = ys0u[(t * 1024 + bbase + bl) * 64 + m];
    }
    __syncthreads();
    float acc[4][4];
#pragma unroll
    for (int q = 0; q < 4; q++)
#pragma unroll
      for (int b = 0; b < 4; b++) acc[q][b] = 0.f;
#pragma unroll
    for (int b = 0; b < 4; b++) {
      const uint4* iu = (const uint4*)&in_u[b][kq * 32];
#pragma unroll
      for (int m = 0; m < 8; m++) {
        uint4 u = iu[m];
#pragma unroll
        for (int q = 0; q < 4; q++) {
          acc[q][b] = fdot2(wreg[q][m].x, u.x, acc[q][b]);
          acc[q][b] = fdot2(wreg[q][m].y, u.y, acc[q][b]);
          acc[q][b] = fdot2(wreg[q][m].z, u.z, acc[q][b]);
          acc[q][b] = fdot2(wreg[q][m].w, u.w, acc[q][b]);
        }
      }
    }
    if (kq > 0) {
#pragma unroll
      for (int b = 0; b < 4; b++)
        part[kq - 1][j][b] = make_float4(acc[0][b], acc[1][b], acc[2][b], acc[3][b]);
    }
    __syncthreads();
    if (kq == 0) {
#pragma unroll
      for (int b = 0; b < 4; b++) {
        float4 p0 = part[0][j][b], p1 = part[1][j][b], p2 = part[2][j][b];
        float gi = acc[0][b] + p0.x + p1.x + p2.x + bsv[0];
        float gf = acc[1][b] + p0.y + p1.y + p2.y + bsv[1];
        float gg = acc[2][b] + p0.z + p1.z + p2.z + bsv[2];
        float go = acc[3][b] + p0.w + p1.w + p2.w + bsv[3];
        float c = sigm(gf) * cst[b] + sigm(gi) * tanhf(gg);
        cst[b] = c;
        float h = sigm(go) * tanhf(c);
        ((__half*)&in_u[b][0])[128 + j] = __float2half_rn(h);
        if (t == 95) enc[(bbase + b) * 128 + j] = h;
      }
    }
  }
}

// ---------------- AR diffusion: MFMA, 16 batches/WG, 4 waves ----------------
// W1 cols: [0:128) enc | [128:134) exo | [134:150) emb | 150 prev_y | 151 y |
//          [152:168) t_e | [168:184) h_e
// lane: m = l&15 (batch for A-side & y-state; n for B/C-side), q = l>>4.
// A-frag (16x16x32_f16): A[m=l&15][k=q*8+j]; lane k-set: k = f*32 + q*8 + j.
// C: col n=l&15, row m=q*4+reg.
__global__ __launch_bounds__(256, 1) void k_diff(
    const float* __restrict__ xfut, const float* __restrict__ y0,
    const int* __restrict__ tix, const float* __restrict__ noise,
    const float* __restrict__ temb, const float* __restrict__ W1,
    const float* __restrict__ b1, const float* __restrict__ b2,
    const float* __restrict__ W3, const float* __restrict__ b3,
    const uint32_t* __restrict__ w2p, const float* __restrict__ enc,
    float* __restrict__ out) {
  __shared__ __align__(16) uint32_t W1sL[128 * 64];   // W1 cols 0..127, fp16 pairs
  __shared__ __align__(16) uint32_t W1xL[128 * 28];   // W1 cols 128..183
  __shared__ __align__(16) uint32_t encPL[16 * 64];   // enc fp16 pairs per batch
  __shared__ uint32_t embPL[16 * 8];                  // emb fp16 pairs per batch
  __shared__ float teL[100][16];
  __shared__ float2 ccL[100];
  __shared__ __align__(16) __half tprojL[100 * 128];  // [t][k]
  __shared__ __half hprojL[8 * 128];                  // [s][k]
  __shared__ __align__(16) float partL[2][4][16];     // [buf][wave][m]
  __shared__ uint32_t encdL[256 * 17];                // per-thread 16 pairs (+pad)

  const int tid = threadIdx.x;
  const int w = tid >> 6, l = tid & 63;
  const int m = l & 15, q = l >> 4;
  const int bbase = blockIdx.x * 16;

  // ---- stage W1 / enc / emb / tables ----
  for (int i = tid; i < 128 * 64; i += 256) {
    int r = i >> 6, c = i & 63;
    W1sL[i] = pack2f(W1[r * 184 + 2 * c], W1[r * 184 + 2 * c + 1]);
  }
  for (int i = tid; i < 128 * 28; i += 256) {
    int r = i / 28, c = i % 28;
    W1xL[i] = pack2f(W1[r * 184 + 128 + 2 * c], W1[r * 184 + 129 + 2 * c]);
  }
  for (int i = tid; i < 16 * 64; i += 256) {
    int bb = i >> 6, c = i & 63;
    encPL[i] = pack2f(enc[(bbase + bb) * 128 + 2 * c], enc[(bbase + bb) * 128 + 2 * c + 1]);
  }
  for (int i = tid; i < 16 * 8; i += 256) {
    int bb = i >> 3, c = i & 7;
    const float* er = temb + tix[bbase + bb] * 16;
    embPL[i] = pack2f(er[2 * c], er[2 * c + 1]);
  }
  for (int p = tid; p < 1600; p += 256) {
    int tt = p >> 4, i = p & 15;
    float f = expf(-logf(10000.f) * (float)(i & 7) / 8.f);
    float a = (float)tt * f;
    teL[tt][i] = (i < 8) ? cosf(a) : sinf(a);
  }
  for (int qq = tid; qq < 100; qq += 256) {
    float ab = 1.f, beta = 0.f;
    for (int i = 0; i <= qq; i++) {
      beta = 1e-4f + (0.02f - 1e-4f) * (float)i / 99.f;
      ab *= (1.f - beta);
    }
    float cs, cd;
    if (qq == 0) { cs = sqrtf(1.f - ab); cd = 1.f / (sqrtf(ab) + 1e-8f); }
    else { cs = beta / (sqrtf(1.f - ab) + 1e-8f); cd = 1.f / (sqrtf(1.f - beta) + 1e-8f); }
    ccL[qq] = make_float2(cs, cd);
  }
  __syncthreads();

  // ---- tproj[t][k] = W1_te(row k).te[t] ; hproj[s][k] = W1_he(row k).te[s] ----
  {
    int k = tid & 127, hs = tid >> 7;   // hs: t-range half
    float wte[16], whe[16];
#pragma unroll
    for (int i = 0; i < 8; i++) {
      float2 a = up2(W1xL[k * 28 + 12 + i]);   // cols 152..167
      wte[2 * i] = a.x; wte[2 * i + 1] = a.y;
      float2 bqq = up2(W1xL[k * 28 + 20 + i]); // cols 168..183
      whe[2 * i] = bqq.x; whe[2 * i + 1] = bqq.y;
    }
    for (int tt = hs * 50; tt < hs * 50 + 50; tt++) {
      float s = 0.f;
#pragma unroll
      for (int i = 0; i < 16; i++) s += wte[i] * teL[tt][i];
      tprojL[tt * 128 + k] = __float2half_rn(s);
    }
    if (hs == 0) {
      for (int ss = 0; ss < 8; ss++) {
        float s = 0.f;
#pragma unroll
        for (int i = 0; i < 16; i++) s += whe[i] * teL[ss][i];
        hprojL[ss * 128 + k] = __float2half_rn(s);
      }
    }
  }

  // ---- per-lane constant part of base: b1 + W1_enc.enc + W1_emb.emb ----
  for (int pi = 0; pi < 16; pi++) {
    int k0 = (pi >> 2) * 32 + q * 8 + (pi & 3) * 2;
    half2_t a0 = {(_Float16)0.f, (_Float16)0.f};
    half2_t a1 = a0;
    const uint32_t* wr0 = &W1sL[k0 * 64];
    const uint32_t* wr1 = &W1sL[(k0 + 1) * 64];
    const uint32_t* ep = &encPL[m * 64];
#pragma unroll 8
    for (int c = 0; c < 64; c++) {
      half2_t e = __builtin_bit_cast(half2_t, ep[c]);
      a0 += __builtin_bit_cast(half2_t, wr0[c]) * e;
      a1 += __builtin_bit_cast(half2_t, wr1[c]) * e;
    }
#pragma unroll
    for (int c = 0; c < 8; c++) {
      half2_t e = __builtin_bit_cast(half2_t, embPL[m * 8 + c]);
      a0 += __builtin_bit_cast(half2_t, W1xL[k0 * 28 + 3 + c]) * e;       // cols 134..149
      a1 += __builtin_bit_cast(half2_t, W1xL[(k0 + 1) * 28 + 3 + c]) * e;
    }
    float e0 = b1[k0] + (float)a0.x + (float)a0.y;
    float e1 = b1[k0 + 1] + (float)a1.x + (float)a1.y;
    encdL[tid * 17 + pi] = pack2f(e0, e1);
  }

  // ---- per-lane resident weights ----
  uint4 Bf[2][4];
  const uint4* w2u4 = (const uint4*)w2p;
#pragma unroll
  for (int tt = 0; tt < 2; tt++) {
    int n = w * 32 + tt * 16 + m;
#pragma unroll
    for (int f = 0; f < 4; f++) Bf[tt][f] = w2u4[n * 16 + f * 4 + q];
  }
  const float w3v0 = W3[w * 32 + m], w3v1 = W3[w * 32 + 16 + m];
  const float b2v0 = b2[w * 32 + m], b2v1 = b2[w * 32 + 16 + m];
  const float b3v = b3[0];

  uint32_t w1yP[16];
#pragma unroll
  for (int pi = 0; pi < 16; pi++) {
    int k0 = (pi >> 2) * 32 + q * 8 + (pi & 3) * 2;
    uint32_t ua = W1xL[k0 * 28 + 11];         // halfs: col150(lo), col151(hi)
    uint32_t ub = W1xL[(k0 + 1) * 28 + 11];
    w1yP[pi] = (ua >> 16) | (ub & 0xFFFF0000u);
  }

  float prev_y = y0[bbase + m];
  __syncthreads();

  int buf = 0;
  for (int s = 0; s < 8; s++) {
    // base pairs for this AR step
    float xf[6];
#pragma unroll
    for (int i = 0; i < 6; i++) xf[i] = xfut[((bbase + m) * 8 + s) * 6 + i];
    uint32_t bph[16];
#pragma unroll
    for (int pi = 0; pi < 16; pi++) {
      int k0 = (pi >> 2) * 32 + q * 8 + (pi & 3) * 2;
      float2 ed = up2(encdL[tid * 17 + pi]);
      float e0 = ed.x, e1 = ed.y;
#pragma unroll
      for (int c = 0; c < 3; c++) {
        float2 w0v = up2(W1xL[k0 * 28 + c]);        // cols 128..133 (exo)
        float2 w1v = up2(W1xL[(k0 + 1) * 28 + c]);
        e0 += w0v.x * xf[2 * c] + w0v.y * xf[2 * c + 1];
        e1 += w1v.x * xf[2 * c] + w1v.y * xf[2 * c + 1];
      }
      e0 += up2(W1xL[k0 * 28 + 11]).x * prev_y;     // col 150
      e1 += up2(W1xL[(k0 + 1) * 28 + 11]).x * prev_y;
      e0 += (float)hprojL[s * 128 + k0];
      e1 += (float)hprojL[s * 128 + k0 + 1];
      bph[pi] = pack2f(e0, e1);
    }

    float y = noise[s * 1024 + bbase + m];
    for (int t = 99; t >= 0; t--) {
      const uint4* tp = (const uint4*)(tprojL + t * 128 + q * 8);
      uint32_t yP = pack2f(y, y);
      v4f c0 = {0.f, 0.f, 0.f, 0.f}, c1 = c0;
#pragma unroll
      for (int f = 0; f < 4; f++) {
        uint4 tv = tp[f * 4];           // +f*32 halfs = +f*4 uint4
        uint4 au;
        au.x = pk_h1(bph[f * 4 + 0], tv.x, w1yP[f * 4 + 0], yP);
        au.y = pk_h1(bph[f * 4 + 1], tv.y, w1yP[f * 4 + 1], yP);
        au.z = pk_h1(bph[f * 4 + 2], tv.z, w1yP[f * 4 + 2], yP);
        au.w = pk_h1(bph[f * 4 + 3], tv.w, w1yP[f * 4 + 3], yP);
        v8h A = __builtin_bit_cast(v8h, au);
        c0 = __builtin_amdgcn_mfma_f32_16x16x32_f16(A, __builtin_bit_cast(v8h, Bf[0][f]), c0, 0, 0, 0);
        c1 = __builtin_amdgcn_mfma_f32_16x16x32_f16(A, __builtin_bit_cast(v8h, Bf[1][f]), c1, 0, 0, 0);
      }
      float pr[4];
#pragma unroll
      for (int r = 0; r < 4; r++) {
        pr[r] = fmaxf(c0[r] + b2v0, 0.f) * w3v0 + fmaxf(c1[r] + b2v1, 0.f) * w3v1;
        pr[r] = rowsum16(pr[r]);
      }
      if ((l & 15) == 15)
        *(float4*)&partL[buf][w][q * 4] = make_float4(pr[0], pr[1], pr[2], pr[3]);
      __syncthreads();
      float2 cc = ccL[t];
      float eps = b3v + partL[buf][0][m] + partL[buf][1][m] +
                  partL[buf][2][m] + partL[buf][3][m];
      y = (y - cc.x * eps) * cc.y;
      buf ^= 1;
    }
    if (w == 0 && l < 16) out[(bbase + l) * 8 + s] = y;
    prev_y = y;
  }
}

// ---------------------------------------------------------------------------
extern "C" void kernel_launch(void* const* d_in, const int* in_sizes, int n_in,
                              void* d_out, int out_size, void* d_ws, size_t ws_size,
                              hipStream_t stream) {
  const float* x_hist    = (const float*)d_in[0];
  const float* x_future  = (const float*)d_in[1];
  const float* y0        = (const float*)d_in[2];
  const int*   turb_idx  = (const int*)d_in[3];
  const float* init_noise = (const float*)d_in[5];
  const float* turb_emb  = (const float*)d_in[6];
  const float* W_ih0     = (const float*)d_in[7];
  const float* W_hh0     = (const float*)d_in[8];
  const float* b_ih0     = (const float*)d_in[9];
  const float* b_hh0     = (const float*)d_in[10];
  const float* W_ih1     = (const float*)d_in[11];
  const float* W_hh1     = (const float*)d_in[12];
  const float* b_ih1     = (const float*)d_in[13];
  const float* b_hh1     = (const float*)d_in[14];
  const float* W1        = (const float*)d_in[15];
  const float* b1        = (const float*)d_in[16];
  const float* W2        = (const float*)d_in[17];
  const float* b2        = (const float*)d_in[18];
  const float* W3        = (const float*)d_in[19];
  const float* b3        = (const float*)d_in[20];

  char* ws = (char*)d_ws;
  uint32_t* xh16 = (uint32_t*)(ws + OFF_XH);
  uint32_t* w0p  = (uint32_t*)(ws + OFF_W0);
  float*    bs0  = (float*)(ws + OFF_BS0);
  uint32_t* w1p  = (uint32_t*)(ws + OFF_W1L);
  float*    bs1  = (float*)(ws + OFF_BS1);
  uint32_t* w2p  = (uint32_t*)(ws + OFF_W2P);
  float*    encf = (float*)(ws + OFF_ENC);
  __half*   ys0h = (__half*)(ws + OFF_YS0);

  k_prep_xh<<<4608, 256, 0, stream>>>(x_hist, turb_idx, turb_emb, xh16);
  k_prep_w<<<452, 256, 0, stream>>>(W_ih0, W_hh0, b_ih0, b_hh0,
                                    W_ih1, W_hh1, b_ih1, b_hh1,
                                    W2, w0p, w1p, w2p, bs0, bs1);
  k_lstm0<<<256, 512, 0, stream>>>(xh16, w0p, bs0, ys0h);
  k_lstm1<<<256, 512, 0, stream>>>((const uint32_t*)ys0h, w1p, bs1, encf);
  k_diff<<<64, 256, 0, stream>>>(x_future, y0, turb_idx, init_noise, turb_emb,
                                 W1, b1, b2, W3, b3, w2p, encf, (float*)d_out);
}

// Round 4
// 724.919 us; speedup vs baseline: 1.9136x; 1.6195x over previous
//
#include <hip/hip_runtime.h>
#include <hip/hip_fp16.h>
#include <stdint.h>

// ---------------------------------------------------------------------------
// Seq2SeqARDiffusion on MI355X.
//   k_prep_xh : pack [x_hist|emb] fp16 inputs for LSTM0, layout [t][b][12 u32]
//   k_prep_w  : pack LSTM weights into MFMA A-fragment order (+ W2, bias sums)
//   k_lstm0   : persistent MFMA LSTM layer 0, 64 WGs x 512 thr, 16 batch/WG
//   k_lstm1   : persistent MFMA LSTM layer 1 -> enc_out, same structure
//   k_diff    : persistent AR-diffusion (round-3 validated, unchanged)
//
// LSTM MFMA scheme: gates[512 x 16b] = W[512 x K] @ in[K x 16b] per step.
//   A-operand = W rows, VGPR-resident, packed so that for lane l (n=l&15,
//   ql=l>>4) of wave w, acc tile T's 4 regs are the i,f,g,o gates of unit
//   j = w*16 + ql*4 + T  -> nonlinearity entirely in registers, no exchange.
//   B-operand = [x|h] in LDS, double-buffered, stride padded to bank floor.
// ---------------------------------------------------------------------------

typedef __attribute__((ext_vector_type(2))) _Float16 half2_t;
typedef __attribute__((ext_vector_type(8))) _Float16 v8h;
typedef __attribute__((ext_vector_type(4))) float v4f;

#define DEV __device__ __forceinline__

DEV uint32_t pack2f(float a, float b) {
  __half ha = __float2half_rn(a), hb = __float2half_rn(b);
  return (uint32_t)__half_as_ushort(ha) | ((uint32_t)__half_as_ushort(hb) << 16);
}

DEV float2 up2(uint32_t u) {
  half2_t h = __builtin_bit_cast(half2_t, u);
  return make_float2((float)h.x, (float)h.y);
}

DEV float fast_ex2(float x) {
#if __has_builtin(__builtin_amdgcn_exp2f)
  return __builtin_amdgcn_exp2f(x);
#else
  return exp2f(x);
#endif
}
DEV float fast_rcp(float x) {
#if __has_builtin(__builtin_amdgcn_rcpf)
  return __builtin_amdgcn_rcpf(x);
#else
  return 1.f / x;
#endif
}
DEV float sigm(float x) { return fast_rcp(1.f + fast_ex2(-1.4426950408889634f * x)); }
DEV float tanh_f(float x) {
  return 2.f * fast_rcp(1.f + fast_ex2(-2.8853900817779268f * x)) - 1.f;
}

// h1 pair = relu(base + tproj + w1y*y), all packed fp16
DEV uint32_t pk_h1(uint32_t b, uint32_t t, uint32_t wy, uint32_t yP) {
  half2_t hb = __builtin_bit_cast(half2_t, b);
  half2_t ht = __builtin_bit_cast(half2_t, t);
  half2_t hw = __builtin_bit_cast(half2_t, wy);
  half2_t hy = __builtin_bit_cast(half2_t, yP);
  half2_t r = hb + ht + hw * hy;
  half2_t z = {(_Float16)0.f, (_Float16)0.f};
#if __has_builtin(__builtin_elementwise_max)
  r = __builtin_elementwise_max(r, z);
#else
  uint32_t u = __builtin_bit_cast(uint32_t, r);
  uint32_t mask = ((u >> 15) & 1u) * 0xFFFFu | ((u >> 31) & 1u) * 0xFFFF0000u;
  r = __builtin_bit_cast(half2_t, u & ~mask);
#endif
  return __builtin_bit_cast(uint32_t, r);
}

// sum over each 16-lane row; lane (l&15)==15 of each row holds the row sum
DEV float rowsum16(float v) {
  int x;
  x = __builtin_amdgcn_update_dpp(0, __builtin_bit_cast(int, v), 0x111, 0xf, 0xf, true);
  v += __builtin_bit_cast(float, x);
  x = __builtin_amdgcn_update_dpp(0, __builtin_bit_cast(int, v), 0x112, 0xf, 0xf, true);
  v += __builtin_bit_cast(float, x);
  x = __builtin_amdgcn_update_dpp(0, __builtin_bit_cast(int, v), 0x114, 0xf, 0xf, true);
  v += __builtin_bit_cast(float, x);
  x = __builtin_amdgcn_update_dpp(0, __builtin_bit_cast(int, v), 0x118, 0xf, 0xf, true);
  v += __builtin_bit_cast(float, x);
  return v;
}

// ---------------- workspace layout (bytes) ----------------
static constexpr size_t OFF_XH  = 0;                 // 96*1024*12 u32 = 4,718,592
static constexpr size_t OFF_W0  = 4718592;           // w0A 40960 u32 = 163,840
static constexpr size_t OFF_BS0 = 4882432;           // 512 f32
static constexpr size_t OFF_W1L = 4884480;           // w1A 65536 u32 = 262,144
static constexpr size_t OFF_BS1 = 5146624;           // 512 f32
static constexpr size_t OFF_W2P = 5148672;           // 128*64 u32 = 32,768
static constexpr size_t OFF_ENC = 5181440;           // 1024*128 f32 = 524,288
static constexpr size_t OFF_YS0 = 5705728;           // 96*1024*128 half = 25,165,824
// total ~30.9 MB

// ---------------- prep: pack [x_hist | emb] as fp16 pairs ----------------
__global__ void k_prep_xh(const float* __restrict__ xh, const int* __restrict__ tix,
                          const float* __restrict__ temb, uint32_t* __restrict__ out) {
  int idx = blockIdx.x * 256 + threadIdx.x;          // 96*1024*12 total
  if (idx >= 96 * 1024 * 12) return;
  int m = idx % 12;
  int tb = idx / 12;
  int b = tb & 1023, t = tb >> 10;
  int k0 = 2 * m, k1 = k0 + 1;
  float v0 = (k0 < 8) ? xh[(b * 96 + t) * 8 + k0] : temb[tix[b] * 16 + (k0 - 8)];
  float v1 = (k1 < 8) ? xh[(b * 96 + t) * 8 + k1] : temb[tix[b] * 16 + (k1 - 8)];
  out[idx] = pack2f(v0, v1);
}

// ---------------- prep: pack weights ----------------
// A-fragment order for LSTM l: flat u32 idx = (((w*4+T)*NF + f)*64 + l)*4 + c
// content: lane l -> m=l&15, qf=l>>4; k = f*32 + qf*8 + 2c+{0,1};
// gate row g = (m&3)*128 + w*16 + (m>>2)*4 + T; K-cat = [x | h] (+ zero pad).
__global__ void k_prep_w(const float* __restrict__ Wih0, const float* __restrict__ Whh0,
                         const float* __restrict__ bih0, const float* __restrict__ bhh0,
                         const float* __restrict__ Wih1, const float* __restrict__ Whh1,
                         const float* __restrict__ bih1, const float* __restrict__ bhh1,
                         const float* __restrict__ W2,
                         uint32_t* __restrict__ w0p, uint32_t* __restrict__ w1p,
                         uint32_t* __restrict__ w2p, float* __restrict__ bs0,
                         float* __restrict__ bs1) {
  int idx = blockIdx.x * 256 + threadIdx.x;
  if (idx < 40960) {                       // w0A: NF=5, K=160 ([x24|h128|pad8])
    int w = idx / 5120;
    int r = idx % 5120;
    int T = r / 1280; r %= 1280;
    int f = r / 256;  r %= 256;
    int l = r >> 2, c = r & 3;
    int m = l & 15, qf = l >> 4;
    int g = (m & 3) * 128 + w * 16 + (m >> 2) * 4 + T;
    int k0 = f * 32 + qf * 8 + 2 * c, k1 = k0 + 1;
    float a = (k0 < 24) ? Wih0[g * 24 + k0] : ((k0 < 152) ? Whh0[g * 128 + k0 - 24] : 0.f);
    float b = (k1 < 24) ? Wih0[g * 24 + k1] : ((k1 < 152) ? Whh0[g * 128 + k1 - 24] : 0.f);
    w0p[idx] = pack2f(a, b);
  } else if (idx < 106496) {               // w1A: NF=8, K=256 ([ys0 128|h128])
    int i = idx - 40960;
    int w = i / 8192;
    int r = i % 8192;
    int T = r / 2048; r %= 2048;
    int f = r / 256;  r %= 256;
    int l = r >> 2, c = r & 3;
    int m = l & 15, qf = l >> 4;
    int g = (m & 3) * 128 + w * 16 + (m >> 2) * 4 + T;
    int k0 = f * 32 + qf * 8 + 2 * c, k1 = k0 + 1;
    float a = (k0 < 128) ? Wih1[g * 128 + k0] : Whh1[g * 128 + k0 - 128];
    float b = (k1 < 128) ? Wih1[g * 128 + k1] : Whh1[g * 128 + k1 - 128];
    w1p[i] = pack2f(a, b);
  } else if (idx < 114688) {               // W2: 128 x 64 u32 (row-major pairs)
    int i = idx - 106496;
    w2p[i] = pack2f(W2[2 * i], W2[2 * i + 1]);
  } else if (idx < 115200) {
    int i = idx - 114688;
    bs0[i] = bih0[i] + bhh0[i];
  } else if (idx < 115712) {
    int i = idx - 115200;
    bs1[i] = bih1[i] + bhh1[i];
  }
}

// ---------------- LSTM layer 0 (MFMA; 16 batch/WG, 64 WGs x 512) ----------------
// in tile: [x(0..23) | h(24..151) | pad(152..159)], stride 160 halfs = 320 B.
__global__ __launch_bounds__(512, 2) void k_lstm0(const uint32_t* __restrict__ xh16,
                                                  const uint32_t* __restrict__ w0A,
                                                  const float* __restrict__ bs0,
                                                  __half* __restrict__ ys0) {
  __shared__ __align__(16) __half inb[2][16][160];
  const int tid = threadIdx.x;
  const int w = tid >> 6, l = tid & 63;
  const int n = l & 15, ql = l >> 4;
  const int ju = w * 16 + ql * 4;
  const int bbase = blockIdx.x * 16;

  uint4 Af[4][5];
#pragma unroll
  for (int T = 0; T < 4; T++)
#pragma unroll
    for (int f = 0; f < 5; f++)
      Af[T][f] = ((const uint4*)w0A)[((w * 4 + T) * 5 + f) * 64 + l];
  float bias[4][4];
#pragma unroll
  for (int T = 0; T < 4; T++)
#pragma unroll
    for (int r = 0; r < 4; r++) bias[T][r] = bs0[r * 128 + ju + T];

  for (int i = tid; i < 2560; i += 512) ((uint32_t*)inb)[i] = 0u;  // zero both bufs
  __syncthreads();
  if (tid < 192) {  // stage x_0 into buf 0
    int b = tid / 12, m = tid % 12;
    ((uint32_t*)&inb[0][b][0])[m] = xh16[(0 * 1024 + bbase + b) * 12 + m];
  }
  float cst[4] = {0.f, 0.f, 0.f, 0.f};
  __syncthreads();

  for (int t = 0; t < 96; t++) {
    const int cur = t & 1, nxt = cur ^ 1;
    uint32_t sx = 0;
    int sb = 0, sm = 0;
    if (t < 95 && tid < 192) {           // prefetch x_{t+1} under the MFMAs
      sb = tid / 12; sm = tid % 12;
      sx = xh16[((t + 1) * 1024 + bbase + sb) * 12 + sm];
    }
    v4f acc[4];
#pragma unroll
    for (int T = 0; T < 4; T++) acc[T] = (v4f){0.f, 0.f, 0.f, 0.f};
#pragma unroll
    for (int f = 0; f < 5; f++) {
      uint4 bu = *(const uint4*)&inb[cur][n][f * 32 + ql * 8];
      v8h Bv = __builtin_bit_cast(v8h, bu);
#pragma unroll
      for (int T = 0; T < 4; T++)
        acc[T] = __builtin_amdgcn_mfma_f32_16x16x32_f16(
            __builtin_bit_cast(v8h, Af[T][f]), Bv, acc[T], 0, 0, 0);
    }
    float hv[4];
#pragma unroll
    for (int T = 0; T < 4; T++) {
      float gi = acc[T][0] + bias[T][0];
      float gf = acc[T][1] + bias[T][1];
      float gg = acc[T][2] + bias[T][2];
      float go = acc[T][3] + bias[T][3];
      float c = sigm(gf) * cst[T] + sigm(gi) * tanh_f(gg);
      cst[T] = c;
      hv[T] = sigm(go) * tanh_f(c);
    }
    uint32_t h01 = pack2f(hv[0], hv[1]), h23 = pack2f(hv[2], hv[3]);
    *(uint2*)&inb[nxt][n][24 + ju] = make_uint2(h01, h23);
    *(uint2*)((__half*)ys0 + (size_t)(t * 1024 + bbase + n) * 128 + ju) = make_uint2(h01, h23);
    if (t < 95 && tid < 192) ((uint32_t*)&inb[nxt][sb][0])[sm] = sx;
    __syncthreads();
  }
}

// ---------------- LSTM layer 1 (MFMA; 16 batch/WG, 64 WGs x 512) ----------------
// in tile: [ys0_t(0..127) | h(128..255) | pad], stride 264 halfs = 528 B.
__global__ __launch_bounds__(512, 2) void k_lstm1(const uint32_t* __restrict__ ys0u,
                                                  const uint32_t* __restrict__ w1A,
                                                  const float* __restrict__ bs1,
                                                  float* __restrict__ enc) {
  __shared__ __align__(16) __half inb[2][16][264];
  const int tid = threadIdx.x;
  const int w = tid >> 6, l = tid & 63;
  const int n = l & 15, ql = l >> 4;
  const int ju = w * 16 + ql * 4;
  const int bbase = blockIdx.x * 16;
  const int sb = tid >> 5, sc = tid & 31;   // staging: batch, 8B-chunk

  uint4 Af[4][8];
#pragma unroll
  for (int T = 0; T < 4; T++)
#pragma unroll
    for (int f = 0; f < 8; f++)
      Af[T][f] = ((const uint4*)w1A)[((w * 4 + T) * 8 + f) * 64 + l];
  float bias[4][4];
#pragma unroll
  for (int T = 0; T < 4; T++)
#pragma unroll
    for (int r = 0; r < 4; r++) bias[T][r] = bs1[r * 128 + ju + T];

  for (int i = tid; i < 4224; i += 512) ((uint32_t*)inb)[i] = 0u;
  __syncthreads();
  {  // stage ys0[t=0] into buf 0
    uint2 v = ((const uint2*)ys0u)[(size_t)(0 * 1024 + bbase + sb) * 32 + sc];
    *(uint2*)&inb[0][sb][sc * 4] = v;
  }
  float cst[4] = {0.f, 0.f, 0.f, 0.f};
  __syncthreads();

  for (int t = 0; t < 96; t++) {
    const int cur = t & 1, nxt = cur ^ 1;
    uint2 sv = make_uint2(0u, 0u);
    if (t < 95)                          // prefetch ys0[t+1] under the MFMAs
      sv = ((const uint2*)ys0u)[(size_t)((t + 1) * 1024 + bbase + sb) * 32 + sc];
    v4f acc[4];
#pragma unroll
    for (int T = 0; T < 4; T++) acc[T] = (v4f){0.f, 0.f, 0.f, 0.f};
#pragma unroll
    for (int f = 0; f < 8; f++) {
      uint4 bu = *(const uint4*)&inb[cur][n][f * 32 + ql * 8];
      v8h Bv = __builtin_bit_cast(v8h, bu);
#pragma unroll
      for (int T = 0; T < 4; T++)
        acc[T] = __builtin_amdgcn_mfma_f32_16x16x32_f16(
            __builtin_bit_cast(v8h, Af[T][f]), Bv, acc[T], 0, 0, 0);
    }
    float hv[4];
#pragma unroll
    for (int T = 0; T < 4; T++) {
      float gi = acc[T][0] + bias[T][0];
      float gf = acc[T][1] + bias[T][1];
      float gg = acc[T][2] + bias[T][2];
      float go = acc[T][3] + bias[T][3];
      float c = sigm(gf) * cst[T] + sigm(gi) * tanh_f(gg);
      cst[T] = c;
      hv[T] = sigm(go) * tanh_f(c);
    }
    *(uint2*)&inb[nxt][n][128 + ju] = make_uint2(pack2f(hv[0], hv[1]), pack2f(hv[2], hv[3]));
    if (t < 95) *(uint2*)&inb[nxt][sb][sc * 4] = sv;
    if (t == 95)
      *(float4*)&enc[(size_t)(bbase + n) * 128 + ju] = make_float4(hv[0], hv[1], hv[2], hv[3]);
    __syncthreads();
  }
}

// ---------------- AR diffusion: MFMA, 16 batches/WG, 4 waves (round-3) ----------
// W1 cols: [0:128) enc | [128:134) exo | [134:150) emb | 150 prev_y | 151 y |
//          [152:168) t_e | [168:184) h_e
__global__ __launch_bounds__(256, 1) void k_diff(
    const float* __restrict__ xfut, const float* __restrict__ y0,
    const int* __restrict__ tix, const float* __restrict__ noise,
    const float* __restrict__ temb, const float* __restrict__ W1,
    const float* __restrict__ b1, const float* __restrict__ b2,
    const float* __restrict__ W3, const float* __restrict__ b3,
    const uint32_t* __restrict__ w2p, const float* __restrict__ enc,
    float* __restrict__ out) {
  __shared__ __align__(16) uint32_t W1sL[128 * 64];   // W1 cols 0..127, fp16 pairs
  __shared__ __align__(16) uint32_t W1xL[128 * 28];   // W1 cols 128..183
  __shared__ __align__(16) uint32_t encPL[16 * 64];   // enc fp16 pairs per batch
  __shared__ uint32_t embPL[16 * 8];                  // emb fp16 pairs per batch
  __shared__ float teL[100][16];
  __shared__ float2 ccL[100];
  __shared__ __align__(16) __half tprojL[100 * 128];  // [t][k]
  __shared__ __half hprojL[8 * 128];                  // [s][k]
  __shared__ __align__(16) float partL[2][4][16];     // [buf][wave][m]
  __shared__ uint32_t encdL[256 * 17];                // per-thread 16 pairs (+pad)

  const int tid = threadIdx.x;
  const int w = tid >> 6, l = tid & 63;
  const int m = l & 15, q = l >> 4;
  const int bbase = blockIdx.x * 16;

  // ---- stage W1 / enc / emb / tables ----
  for (int i = tid; i < 128 * 64; i += 256) {
    int r = i >> 6, c = i & 63;
    W1sL[i] = pack2f(W1[r * 184 + 2 * c], W1[r * 184 + 2 * c + 1]);
  }
  for (int i = tid; i < 128 * 28; i += 256) {
    int r = i / 28, c = i % 28;
    W1xL[i] = pack2f(W1[r * 184 + 128 + 2 * c], W1[r * 184 + 129 + 2 * c]);
  }
  for (int i = tid; i < 16 * 64; i += 256) {
    int bb = i >> 6, c = i & 63;
    encPL[i] = pack2f(enc[(bbase + bb) * 128 + 2 * c], enc[(bbase + bb) * 128 + 2 * c + 1]);
  }
  for (int i = tid; i < 16 * 8; i += 256) {
    int bb = i >> 3, c = i & 7;
    const float* er = temb + tix[bbase + bb] * 16;
    embPL[i] = pack2f(er[2 * c], er[2 * c + 1]);
  }
  for (int p = tid; p < 1600; p += 256) {
    int tt = p >> 4, i = p & 15;
    float f = expf(-logf(10000.f) * (float)(i & 7) / 8.f);
    float a = (float)tt * f;
    teL[tt][i] = (i < 8) ? cosf(a) : sinf(a);
  }
  for (int qq = tid; qq < 100; qq += 256) {
    float ab = 1.f, beta = 0.f;
    for (int i = 0; i <= qq; i++) {
      beta = 1e-4f + (0.02f - 1e-4f) * (float)i / 99.f;
      ab *= (1.f - beta);
    }
    float cs, cd;
    if (qq == 0) { cs = sqrtf(1.f - ab); cd = 1.f / (sqrtf(ab) + 1e-8f); }
    else { cs = beta / (sqrtf(1.f - ab) + 1e-8f); cd = 1.f / (sqrtf(1.f - beta) + 1e-8f); }
    ccL[qq] = make_float2(cs, cd);
  }
  __syncthreads();

  // ---- tproj[t][k] = W1_te(row k).te[t] ; hproj[s][k] = W1_he(row k).te[s] ----
  {
    int k = tid & 127, hs = tid >> 7;   // hs: t-range half
    float wte[16], whe[16];
#pragma unroll
    for (int i = 0; i < 8; i++) {
      float2 a = up2(W1xL[k * 28 + 12 + i]);   // cols 152..167
      wte[2 * i] = a.x; wte[2 * i + 1] = a.y;
      float2 bqq = up2(W1xL[k * 28 + 20 + i]); // cols 168..183
      whe[2 * i] = bqq.x; whe[2 * i + 1] = bqq.y;
    }
    for (int tt = hs * 50; tt < hs * 50 + 50; tt++) {
      float s = 0.f;
#pragma unroll
      for (int i = 0; i < 16; i++) s += wte[i] * teL[tt][i];
      tprojL[tt * 128 + k] = __float2half_rn(s);
    }
    if (hs == 0) {
      for (int ss = 0; ss < 8; ss++) {
        float s = 0.f;
#pragma unroll
        for (int i = 0; i < 16; i++) s += whe[i] * teL[ss][i];
        hprojL[ss * 128 + k] = __float2half_rn(s);
      }
    }
  }

  // ---- per-lane constant part of base: b1 + W1_enc.enc + W1_emb.emb ----
  for (int pi = 0; pi < 16; pi++) {
    int k0 = (pi >> 2) * 32 + q * 8 + (pi & 3) * 2;
    half2_t a0 = {(_Float16)0.f, (_Float16)0.f};
    half2_t a1 = a0;
    const uint32_t* wr0 = &W1sL[k0 * 64];
    const uint32_t* wr1 = &W1sL[(k0 + 1) * 64];
    const uint32_t* ep = &encPL[m * 64];
#pragma unroll 8
    for (int c = 0; c < 64; c++) {
      half2_t e = __builtin_bit_cast(half2_t, ep[c]);
      a0 += __builtin_bit_cast(half2_t, wr0[c]) * e;
      a1 += __builtin_bit_cast(half2_t, wr1[c]) * e;
    }
#pragma unroll
    for (int c = 0; c < 8; c++) {
      half2_t e = __builtin_bit_cast(half2_t, embPL[m * 8 + c]);
      a0 += __builtin_bit_cast(half2_t, W1xL[k0 * 28 + 3 + c]) * e;       // cols 134..149
      a1 += __builtin_bit_cast(half2_t, W1xL[(k0 + 1) * 28 + 3 + c]) * e;
    }
    float e0 = b1[k0] + (float)a0.x + (float)a0.y;
    float e1 = b1[k0 + 1] + (float)a1.x + (float)a1.y;
    encdL[tid * 17 + pi] = pack2f(e0, e1);
  }

  // ---- per-lane resident weights ----
  uint4 Bf[2][4];
  const uint4* w2u4 = (const uint4*)w2p;
#pragma unroll
  for (int tt = 0; tt < 2; tt++) {
    int n = w * 32 + tt * 16 + m;
#pragma unroll
    for (int f = 0; f < 4; f++) Bf[tt][f] = w2u4[n * 16 + f * 4 + q];
  }
  const float w3v0 = W3[w * 32 + m], w3v1 = W3[w * 32 + 16 + m];
  const float b2v0 = b2[w * 32 + m], b2v1 = b2[w * 32 + 16 + m];
  const float b3v = b3[0];

  uint32_t w1yP[16];
#pragma unroll
  for (int pi = 0; pi < 16; pi++) {
    int k0 = (pi >> 2) * 32 + q * 8 + (pi & 3) * 2;
    uint32_t ua = W1xL[k0 * 28 + 11];         // halfs: col150(lo), col151(hi)
    uint32_t ub = W1xL[(k0 + 1) * 28 + 11];
    w1yP[pi] = (ua >> 16) | (ub & 0xFFFF0000u);
  }

  float prev_y = y0[bbase + m];
  __syncthreads();

  int buf = 0;
  for (int s = 0; s < 8; s++) {
    // base pairs for this AR step
    float xf[6];
#pragma unroll
    for (int i = 0; i < 6; i++) xf[i] = xfut[((bbase + m) * 8 + s) * 6 + i];
    uint32_t bph[16];
#pragma unroll
    for (int pi = 0; pi < 16; pi++) {
      int k0 = (pi >> 2) * 32 + q * 8 + (pi & 3) * 2;
      float2 ed = up2(encdL[tid * 17 + pi]);
      float e0 = ed.x, e1 = ed.y;
#pragma unroll
      for (int c = 0; c < 3; c++) {
        float2 w0v = up2(W1xL[k0 * 28 + c]);        // cols 128..133 (exo)
        float2 w1v = up2(W1xL[(k0 + 1) * 28 + c]);
        e0 += w0v.x * xf[2 * c] + w0v.y * xf[2 * c + 1];
        e1 += w1v.x * xf[2 * c] + w1v.y * xf[2 * c + 1];
      }
      e0 += up2(W1xL[k0 * 28 + 11]).x * prev_y;     // col 150
      e1 += up2(W1xL[(k0 + 1) * 28 + 11]).x * prev_y;
      e0 += (float)hprojL[s * 128 + k0];
      e1 += (float)hprojL[s * 128 + k0 + 1];
      bph[pi] = pack2f(e0, e1);
    }

    float y = noise[s * 1024 + bbase + m];
    for (int t = 99; t >= 0; t--) {
      const uint4* tp = (const uint4*)(tprojL + t * 128 + q * 8);
      uint32_t yP = pack2f(y, y);
      v4f c0 = {0.f, 0.f, 0.f, 0.f}, c1 = c0;
#pragma unroll
      for (int f = 0; f < 4; f++) {
        uint4 tv = tp[f * 4];           // +f*32 halfs = +f*4 uint4
        uint4 au;
        au.x = pk_h1(bph[f * 4 + 0], tv.x, w1yP[f * 4 + 0], yP);
        au.y = pk_h1(bph[f * 4 + 1], tv.y, w1yP[f * 4 + 1], yP);
        au.z = pk_h1(bph[f * 4 + 2], tv.z, w1yP[f * 4 + 2], yP);
        au.w = pk_h1(bph[f * 4 + 3], tv.w, w1yP[f * 4 + 3], yP);
        v8h A = __builtin_bit_cast(v8h, au);
        c0 = __builtin_amdgcn_mfma_f32_16x16x32_f16(A, __builtin_bit_cast(v8h, Bf[0][f]), c0, 0, 0, 0);
        c1 = __builtin_amdgcn_mfma_f32_16x16x32_f16(A, __builtin_bit_cast(v8h, Bf[1][f]), c1, 0, 0, 0);
      }
      float pr[4];
#pragma unroll
      for (int r = 0; r < 4; r++) {
        pr[r] = fmaxf(c0[r] + b2v0, 0.f) * w3v0 + fmaxf(c1[r] + b2v1, 0.f) * w3v1;
        pr[r] = rowsum16(pr[r]);
      }
      if ((l & 15) == 15)
        *(float4*)&partL[buf][w][q * 4] = make_float4(pr[0], pr[1], pr[2], pr[3]);
      __syncthreads();
      float2 cc = ccL[t];
      float eps = b3v + partL[buf][0][m] + partL[buf][1][m] +
                  partL[buf][2][m] + partL[buf][3][m];
      y = (y - cc.x * eps) * cc.y;
      buf ^= 1;
    }
    if (w == 0 && l < 16) out[(bbase + l) * 8 + s] = y;
    prev_y = y;
  }
}

// ---------------------------------------------------------------------------
extern "C" void kernel_launch(void* const* d_in, const int* in_sizes, int n_in,
                              void* d_out, int out_size, void* d_ws, size_t ws_size,
                              hipStream_t stream) {
  const float* x_hist    = (const float*)d_in[0];
  const float* x_future  = (const float*)d_in[1];
  const float* y0        = (const float*)d_in[2];
  const int*   turb_idx  = (const int*)d_in[3];
  const float* init_noise = (const float*)d_in[5];
  const float* turb_emb  = (const float*)d_in[6];
  const float* W_ih0     = (const float*)d_in[7];
  const float* W_hh0     = (const float*)d_in[8];
  const float* b_ih0     = (const float*)d_in[9];
  const float* b_hh0     = (const float*)d_in[10];
  const float* W_ih1     = (const float*)d_in[11];
  const float* W_hh1     = (const float*)d_in[12];
  const float* b_ih1     = (const float*)d_in[13];
  const float* b_hh1     = (const float*)d_in[14];
  const float* W1        = (const float*)d_in[15];
  const float* b1        = (const float*)d_in[16];
  const float* W2        = (const float*)d_in[17];
  const float* b2        = (const float*)d_in[18];
  const float* W3        = (const float*)d_in[19];
  const float* b3        = (const float*)d_in[20];

  char* ws = (char*)d_ws;
  uint32_t* xh16 = (uint32_t*)(ws + OFF_XH);
  uint32_t* w0p  = (uint32_t*)(ws + OFF_W0);
  float*    bs0  = (float*)(ws + OFF_BS0);
  uint32_t* w1p  = (uint32_t*)(ws + OFF_W1L);
  float*    bs1  = (float*)(ws + OFF_BS1);
  uint32_t* w2p  = (uint32_t*)(ws + OFF_W2P);
  float*    encf = (float*)(ws + OFF_ENC);
  __half*   ys0h = (__half*)(ws + OFF_YS0);

  k_prep_xh<<<4608, 256, 0, stream>>>(x_hist, turb_idx, turb_emb, xh16);
  k_prep_w<<<452, 256, 0, stream>>>(W_ih0, W_hh0, b_ih0, b_hh0,
                                    W_ih1, W_hh1, b_ih1, b_hh1,
                                    W2, w0p, w1p, w2p, bs0, bs1);
  k_lstm0<<<64, 512, 0, stream>>>(xh16, w0p, bs0, ys0h);
  k_lstm1<<<64, 512, 0, stream>>>((const uint32_t*)ys0h, w1p, bs1, encf);
  k_diff<<<64, 256, 0, stream>>>(x_future, y0, turb_idx, init_noise, turb_emb,
                                 W1, b1, b2, W3, b3, w2p, encf, (float*)d_out);
}

// Round 5
// 675.654 us; speedup vs baseline: 2.0531x; 1.0729x over previous
//
#include <hip/hip_runtime.h>
#include <hip/hip_fp16.h>
#include <stdint.h>

// ---------------------------------------------------------------------------
// Seq2SeqARDiffusion on MI355X.
//   k_prep_xh : pack [x_hist|emb] fp16 inputs for LSTM0, layout [t][b][12 u32]
//   k_prep_w  : pack LSTM weights into MFMA A-fragment order (+ W2, bias sums)
//   k_lstm0   : persistent MFMA LSTM layer 0, 64 WGs x 512 thr, 16 batch/WG
//   k_lstm1   : persistent MFMA LSTM layer 1 -> enc_out, same structure
//   k_diff    : persistent AR-diffusion, 64 WGs x 256 thr; round-5: prefetch
//               rotation (tproj/cc), bt=bph+tproj off-chain, split MFMA
//               accumulators (dep 4->2), bank-padded LDS strides.
// ---------------------------------------------------------------------------

typedef __attribute__((ext_vector_type(2))) _Float16 half2_t;
typedef __attribute__((ext_vector_type(8))) _Float16 v8h;
typedef __attribute__((ext_vector_type(4))) float v4f;

#define DEV __device__ __forceinline__

DEV uint32_t pack2f(float a, float b) {
  __half ha = __float2half_rn(a), hb = __float2half_rn(b);
  return (uint32_t)__half_as_ushort(ha) | ((uint32_t)__half_as_ushort(hb) << 16);
}

DEV float2 up2(uint32_t u) {
  half2_t h = __builtin_bit_cast(half2_t, u);
  return make_float2((float)h.x, (float)h.y);
}

DEV float fast_ex2(float x) {
#if __has_builtin(__builtin_amdgcn_exp2f)
  return __builtin_amdgcn_exp2f(x);
#else
  return exp2f(x);
#endif
}
DEV float fast_rcp(float x) {
#if __has_builtin(__builtin_amdgcn_rcpf)
  return __builtin_amdgcn_rcpf(x);
#else
  return 1.f / x;
#endif
}
DEV float sigm(float x) { return fast_rcp(1.f + fast_ex2(-1.4426950408889634f * x)); }
DEV float tanh_f(float x) {
  return 2.f * fast_rcp(1.f + fast_ex2(-2.8853900817779268f * x)) - 1.f;
}

DEV uint32_t pk_add(uint32_t a, uint32_t b) {
  return __builtin_bit_cast(uint32_t,
      __builtin_bit_cast(half2_t, a) + __builtin_bit_cast(half2_t, b));
}

// relu(w*y + b), packed fp16
DEV uint32_t pk_relufma(uint32_t w, uint32_t y, uint32_t b) {
  half2_t r = __builtin_bit_cast(half2_t, w) * __builtin_bit_cast(half2_t, y) +
              __builtin_bit_cast(half2_t, b);
  half2_t z = {(_Float16)0.f, (_Float16)0.f};
#if __has_builtin(__builtin_elementwise_max)
  r = __builtin_elementwise_max(r, z);
#else
  uint32_t u = __builtin_bit_cast(uint32_t, r);
  uint32_t mask = ((u >> 15) & 1u) * 0xFFFFu | ((u >> 31) & 1u) * 0xFFFF0000u;
  r = __builtin_bit_cast(half2_t, u & ~mask);
#endif
  return __builtin_bit_cast(uint32_t, r);
}

DEV uint32_t cvtpk(float y) {
#if __has_builtin(__builtin_amdgcn_cvt_pkrtz)
  return __builtin_bit_cast(uint32_t, __builtin_amdgcn_cvt_pkrtz(y, y));
#else
  return pack2f(y, y);
#endif
}

// sum over each 16-lane row; lane (l&15)==15 of each row holds the row sum
DEV float rowsum16(float v) {
  int x;
  x = __builtin_amdgcn_update_dpp(0, __builtin_bit_cast(int, v), 0x111, 0xf, 0xf, true);
  v += __builtin_bit_cast(float, x);
  x = __builtin_amdgcn_update_dpp(0, __builtin_bit_cast(int, v), 0x112, 0xf, 0xf, true);
  v += __builtin_bit_cast(float, x);
  x = __builtin_amdgcn_update_dpp(0, __builtin_bit_cast(int, v), 0x114, 0xf, 0xf, true);
  v += __builtin_bit_cast(float, x);
  x = __builtin_amdgcn_update_dpp(0, __builtin_bit_cast(int, v), 0x118, 0xf, 0xf, true);
  v += __builtin_bit_cast(float, x);
  return v;
}

// ---------------- workspace layout (bytes) ----------------
static constexpr size_t OFF_XH  = 0;                 // 96*1024*12 u32 = 4,718,592
static constexpr size_t OFF_W0  = 4718592;           // w0A 40960 u32 = 163,840
static constexpr size_t OFF_BS0 = 4882432;           // 512 f32
static constexpr size_t OFF_W1L = 4884480;           // w1A 65536 u32 = 262,144
static constexpr size_t OFF_BS1 = 5146624;           // 512 f32
static constexpr size_t OFF_W2P = 5148672;           // 128*64 u32 = 32,768
static constexpr size_t OFF_ENC = 5181440;           // 1024*128 f32 = 524,288
static constexpr size_t OFF_YS0 = 5705728;           // 96*1024*128 half = 25,165,824
// total ~30.9 MB

// ---------------- prep: pack [x_hist | emb] as fp16 pairs ----------------
__global__ void k_prep_xh(const float* __restrict__ xh, const int* __restrict__ tix,
                          const float* __restrict__ temb, uint32_t* __restrict__ out) {
  int idx = blockIdx.x * 256 + threadIdx.x;          // 96*1024*12 total
  if (idx >= 96 * 1024 * 12) return;
  int m = idx % 12;
  int tb = idx / 12;
  int b = tb & 1023, t = tb >> 10;
  int k0 = 2 * m, k1 = k0 + 1;
  float v0 = (k0 < 8) ? xh[(b * 96 + t) * 8 + k0] : temb[tix[b] * 16 + (k0 - 8)];
  float v1 = (k1 < 8) ? xh[(b * 96 + t) * 8 + k1] : temb[tix[b] * 16 + (k1 - 8)];
  out[idx] = pack2f(v0, v1);
}

// ---------------- prep: pack weights ----------------
// A-fragment order for LSTM l: flat u32 idx = (((w*4+T)*NF + f)*64 + l)*4 + c
// content: lane l -> m=l&15, qf=l>>4; k = f*32 + qf*8 + 2c+{0,1};
// gate row g = (m&3)*128 + w*16 + (m>>2)*4 + T; K-cat = [x | h] (+ zero pad).
__global__ void k_prep_w(const float* __restrict__ Wih0, const float* __restrict__ Whh0,
                         const float* __restrict__ bih0, const float* __restrict__ bhh0,
                         const float* __restrict__ Wih1, const float* __restrict__ Whh1,
                         const float* __restrict__ bih1, const float* __restrict__ bhh1,
                         const float* __restrict__ W2,
                         uint32_t* __restrict__ w0p, uint32_t* __restrict__ w1p,
                         uint32_t* __restrict__ w2p, float* __restrict__ bs0,
                         float* __restrict__ bs1) {
  int idx = blockIdx.x * 256 + threadIdx.x;
  if (idx < 40960) {                       // w0A: NF=5, K=160 ([x24|h128|pad8])
    int w = idx / 5120;
    int r = idx % 5120;
    int T = r / 1280; r %= 1280;
    int f = r / 256;  r %= 256;
    int l = r >> 2, c = r & 3;
    int m = l & 15, qf = l >> 4;
    int g = (m & 3) * 128 + w * 16 + (m >> 2) * 4 + T;
    int k0 = f * 32 + qf * 8 + 2 * c, k1 = k0 + 1;
    float a = (k0 < 24) ? Wih0[g * 24 + k0] : ((k0 < 152) ? Whh0[g * 128 + k0 - 24] : 0.f);
    float b = (k1 < 24) ? Wih0[g * 24 + k1] : ((k1 < 152) ? Whh0[g * 128 + k1 - 24] : 0.f);
    w0p[idx] = pack2f(a, b);
  } else if (idx < 106496) {               // w1A: NF=8, K=256 ([ys0 128|h128])
    int i = idx - 40960;
    int w = i / 8192;
    int r = i % 8192;
    int T = r / 2048; r %= 2048;
    int f = r / 256;  r %= 256;
    int l = r >> 2, c = r & 3;
    int m = l & 15, qf = l >> 4;
    int g = (m & 3) * 128 + w * 16 + (m >> 2) * 4 + T;
    int k0 = f * 32 + qf * 8 + 2 * c, k1 = k0 + 1;
    float a = (k0 < 128) ? Wih1[g * 128 + k0] : Whh1[g * 128 + k0 - 128];
    float b = (k1 < 128) ? Wih1[g * 128 + k1] : Whh1[g * 128 + k1 - 128];
    w1p[i] = pack2f(a, b);
  } else if (idx < 114688) {               // W2: 128 x 64 u32 (row-major pairs)
    int i = idx - 106496;
    w2p[i] = pack2f(W2[2 * i], W2[2 * i + 1]);
  } else if (idx < 115200) {
    int i = idx - 114688;
    bs0[i] = bih0[i] + bhh0[i];
  } else if (idx < 115712) {
    int i = idx - 115200;
    bs1[i] = bih1[i] + bhh1[i];
  }
}

// ---------------- LSTM layer 0 (MFMA; 16 batch/WG, 64 WGs x 512) ----------------
// in tile: [x(0..23) | h(24..151) | pad(152..159)], stride 160 halfs = 320 B.
__global__ __launch_bounds__(512, 2) void k_lstm0(const uint32_t* __restrict__ xh16,
                                                  const uint32_t* __restrict__ w0A,
                                                  const float* __restrict__ bs0,
                                                  __half* __restrict__ ys0) {
  __shared__ __align__(16) __half inb[2][16][160];
  const int tid = threadIdx.x;
  const int w = tid >> 6, l = tid & 63;
  const int n = l & 15, ql = l >> 4;
  const int ju = w * 16 + ql * 4;
  const int bbase = blockIdx.x * 16;

  uint4 Af[4][5];
#pragma unroll
  for (int T = 0; T < 4; T++)
#pragma unroll
    for (int f = 0; f < 5; f++)
      Af[T][f] = ((const uint4*)w0A)[((w * 4 + T) * 5 + f) * 64 + l];
  float bias[4][4];
#pragma unroll
  for (int T = 0; T < 4; T++)
#pragma unroll
    for (int r = 0; r < 4; r++) bias[T][r] = bs0[r * 128 + ju + T];

  for (int i = tid; i < 2560; i += 512) ((uint32_t*)inb)[i] = 0u;  // zero both bufs
  __syncthreads();
  if (tid < 192) {  // stage x_0 into buf 0
    int b = tid / 12, m = tid % 12;
    ((uint32_t*)&inb[0][b][0])[m] = xh16[(0 * 1024 + bbase + b) * 12 + m];
  }
  float cst[4] = {0.f, 0.f, 0.f, 0.f};
  __syncthreads();

  for (int t = 0; t < 96; t++) {
    const int cur = t & 1, nxt = cur ^ 1;
    uint32_t sx = 0;
    int sb = 0, sm = 0;
    if (t < 95 && tid < 192) {           // prefetch x_{t+1} under the MFMAs
      sb = tid / 12; sm = tid % 12;
      sx = xh16[((t + 1) * 1024 + bbase + sb) * 12 + sm];
    }
    v4f acc[4];
#pragma unroll
    for (int T = 0; T < 4; T++) acc[T] = (v4f){0.f, 0.f, 0.f, 0.f};
#pragma unroll
    for (int f = 0; f < 5; f++) {
      uint4 bu = *(const uint4*)&inb[cur][n][f * 32 + ql * 8];
      v8h Bv = __builtin_bit_cast(v8h, bu);
#pragma unroll
      for (int T = 0; T < 4; T++)
        acc[T] = __builtin_amdgcn_mfma_f32_16x16x32_f16(
            __builtin_bit_cast(v8h, Af[T][f]), Bv, acc[T], 0, 0, 0);
    }
    float hv[4];
#pragma unroll
    for (int T = 0; T < 4; T++) {
      float gi = acc[T][0] + bias[T][0];
      float gf = acc[T][1] + bias[T][1];
      float gg = acc[T][2] + bias[T][2];
      float go = acc[T][3] + bias[T][3];
      float c = sigm(gf) * cst[T] + sigm(gi) * tanh_f(gg);
      cst[T] = c;
      hv[T] = sigm(go) * tanh_f(c);
    }
    uint32_t h01 = pack2f(hv[0], hv[1]), h23 = pack2f(hv[2], hv[3]);
    *(uint2*)&inb[nxt][n][24 + ju] = make_uint2(h01, h23);
    *(uint2*)((__half*)ys0 + (size_t)(t * 1024 + bbase + n) * 128 + ju) = make_uint2(h01, h23);
    if (t < 95 && tid < 192) ((uint32_t*)&inb[nxt][sb][0])[sm] = sx;
    __syncthreads();
  }
}

// ---------------- LSTM layer 1 (MFMA; 16 batch/WG, 64 WGs x 512) ----------------
// in tile: [ys0_t(0..127) | h(128..255) | pad], stride 264 halfs = 528 B.
__global__ __launch_bounds__(512, 2) void k_lstm1(const uint32_t* __restrict__ ys0u,
                                                  const uint32_t* __restrict__ w1A,
                                                  const float* __restrict__ bs1,
                                                  float* __restrict__ enc) {
  __shared__ __align__(16) __half inb[2][16][264];
  const int tid = threadIdx.x;
  const int w = tid >> 6, l = tid & 63;
  const int n = l & 15, ql = l >> 4;
  const int ju = w * 16 + ql * 4;
  const int bbase = blockIdx.x * 16;
  const int sb = tid >> 5, sc = tid & 31;   // staging: batch, 8B-chunk

  uint4 Af[4][8];
#pragma unroll
  for (int T = 0; T < 4; T++)
#pragma unroll
    for (int f = 0; f < 8; f++)
      Af[T][f] = ((const uint4*)w1A)[((w * 4 + T) * 8 + f) * 64 + l];
  float bias[4][4];
#pragma unroll
  for (int T = 0; T < 4; T++)
#pragma unroll
    for (int r = 0; r < 4; r++) bias[T][r] = bs1[r * 128 + ju + T];

  for (int i = tid; i < 4224; i += 512) ((uint32_t*)inb)[i] = 0u;
  __syncthreads();
  {  // stage ys0[t=0] into buf 0
    uint2 v = ((const uint2*)ys0u)[(size_t)(0 * 1024 + bbase + sb) * 32 + sc];
    *(uint2*)&inb[0][sb][sc * 4] = v;
  }
  float cst[4] = {0.f, 0.f, 0.f, 0.f};
  __syncthreads();

  for (int t = 0; t < 96; t++) {
    const int cur = t & 1, nxt = cur ^ 1;
    uint2 sv = make_uint2(0u, 0u);
    if (t < 95)                          // prefetch ys0[t+1] under the MFMAs
      sv = ((const uint2*)ys0u)[(size_t)((t + 1) * 1024 + bbase + sb) * 32 + sc];
    v4f acc[4];
#pragma unroll
    for (int T = 0; T < 4; T++) acc[T] = (v4f){0.f, 0.f, 0.f, 0.f};
#pragma unroll
    for (int f = 0; f < 8; f++) {
      uint4 bu = *(const uint4*)&inb[cur][n][f * 32 + ql * 8];
      v8h Bv = __builtin_bit_cast(v8h, bu);
#pragma unroll
      for (int T = 0; T < 4; T++)
        acc[T] = __builtin_amdgcn_mfma_f32_16x16x32_f16(
            __builtin_bit_cast(v8h, Af[T][f]), Bv, acc[T], 0, 0, 0);
    }
    float hv[4];
#pragma unroll
    for (int T = 0; T < 4; T++) {
      float gi = acc[T][0] + bias[T][0];
      float gf = acc[T][1] + bias[T][1];
      float gg = acc[T][2] + bias[T][2];
      float go = acc[T][3] + bias[T][3];
      float c = sigm(gf) * cst[T] + sigm(gi) * tanh_f(gg);
      cst[T] = c;
      hv[T] = sigm(go) * tanh_f(c);
    }
    *(uint2*)&inb[nxt][n][128 + ju] = make_uint2(pack2f(hv[0], hv[1]), pack2f(hv[2], hv[3]));
    if (t < 95) *(uint2*)&inb[nxt][sb][sc * 4] = sv;
    if (t == 95)
      *(float4*)&enc[(size_t)(bbase + n) * 128 + ju] = make_float4(hv[0], hv[1], hv[2], hv[3]);
    __syncthreads();
  }
}

// ---------------- AR diffusion: MFMA, 16 batches/WG, 4 waves ----------------
// W1 cols: [0:128) enc | [128:134) exo | [134:150) emb | 150 prev_y | 151 y |
//          [152:168) t_e | [168:184) h_e
// Round 5: tproj/cc prefetch rotation, bt=bph+tproj computed off the critical
// path, split MFMA accumulators, bank-padded LDS strides (65/29/65/9).
__global__ __launch_bounds__(256, 1) void k_diff(
    const float* __restrict__ xfut, const float* __restrict__ y0,
    const int* __restrict__ tix, const float* __restrict__ noise,
    const float* __restrict__ temb, const float* __restrict__ W1,
    const float* __restrict__ b1, const float* __restrict__ b2,
    const float* __restrict__ W3, const float* __restrict__ b3,
    const uint32_t* __restrict__ w2p, const float* __restrict__ enc,
    float* __restrict__ out) {
  __shared__ uint32_t W1sL[128 * 65];                 // W1 cols 0..127 (stride 65)
  __shared__ uint32_t W1xL[128 * 29];                 // W1 cols 128..183 (stride 29)
  __shared__ uint32_t encPL[16 * 65];                 // enc fp16 pairs (stride 65)
  __shared__ uint32_t embPL[16 * 9];                  // emb fp16 pairs (stride 9)
  __shared__ float teL[100][16];
  __shared__ float2 ccL[100];
  __shared__ __align__(16) __half tprojL[100 * 128];  // [t][k]
  __shared__ __half hprojL[8 * 128];                  // [s][k]
  __shared__ __align__(16) float partL[2][4][16];     // [buf][wave][m]
  __shared__ uint32_t encdL[256 * 17];                // per-thread 16 pairs (+pad)

  const int tid = threadIdx.x;
  const int w = tid >> 6, l = tid & 63;
  const int m = l & 15, q = l >> 4;
  const int bbase = blockIdx.x * 16;

  // ---- stage W1 / enc / emb / tables ----
  for (int i = tid; i < 128 * 64; i += 256) {
    int r = i >> 6, c = i & 63;
    W1sL[r * 65 + c] = pack2f(W1[r * 184 + 2 * c], W1[r * 184 + 2 * c + 1]);
  }
  for (int i = tid; i < 128 * 28; i += 256) {
    int r = i / 28, c = i % 28;
    W1xL[r * 29 + c] = pack2f(W1[r * 184 + 128 + 2 * c], W1[r * 184 + 129 + 2 * c]);
  }
  for (int i = tid; i < 16 * 64; i += 256) {
    int bb = i >> 6, c = i & 63;
    encPL[bb * 65 + c] = pack2f(enc[(bbase + bb) * 128 + 2 * c],
                                enc[(bbase + bb) * 128 + 2 * c + 1]);
  }
  for (int i = tid; i < 16 * 8; i += 256) {
    int bb = i >> 3, c = i & 7;
    const float* er = temb + tix[bbase + bb] * 16;
    embPL[bb * 9 + c] = pack2f(er[2 * c], er[2 * c + 1]);
  }
  for (int p = tid; p < 1600; p += 256) {
    int tt = p >> 4, i = p & 15;
    float f = expf(-logf(10000.f) * (float)(i & 7) / 8.f);
    float a = (float)tt * f;
    teL[tt][i] = (i < 8) ? cosf(a) : sinf(a);
  }
  for (int qq = tid; qq < 100; qq += 256) {
    float ab = 1.f, beta = 0.f;
    for (int i = 0; i <= qq; i++) {
      beta = 1e-4f + (0.02f - 1e-4f) * (float)i / 99.f;
      ab *= (1.f - beta);
    }
    float cs, cd;
    if (qq == 0) { cs = sqrtf(1.f - ab); cd = 1.f / (sqrtf(ab) + 1e-8f); }
    else { cs = beta / (sqrtf(1.f - ab) + 1e-8f); cd = 1.f / (sqrtf(1.f - beta) + 1e-8f); }
    ccL[qq] = make_float2(cs, cd);
  }
  __syncthreads();

  // ---- tproj[t][k] = W1_te(row k).te[t] ; hproj[s][k] = W1_he(row k).te[s] ----
  {
    int k = tid & 127, hs = tid >> 7;   // hs: t-range half
    float wte[16], whe[16];
#pragma unroll
    for (int i = 0; i < 8; i++) {
      float2 a = up2(W1xL[k * 29 + 12 + i]);   // cols 152..167
      wte[2 * i] = a.x; wte[2 * i + 1] = a.y;
      float2 bqq = up2(W1xL[k * 29 + 20 + i]); // cols 168..183
      whe[2 * i] = bqq.x; whe[2 * i + 1] = bqq.y;
    }
    for (int tt = hs * 50; tt < hs * 50 + 50; tt++) {
      float s = 0.f;
#pragma unroll
      for (int i = 0; i < 16; i++) s += wte[i] * teL[tt][i];
      tprojL[tt * 128 + k] = __float2half_rn(s);
    }
    if (hs == 0) {
      for (int ss = 0; ss < 8; ss++) {
        float s = 0.f;
#pragma unroll
        for (int i = 0; i < 16; i++) s += whe[i] * teL[ss][i];
        hprojL[ss * 128 + k] = __float2half_rn(s);
      }
    }
  }

  // ---- per-lane constant part of base: b1 + W1_enc.enc + W1_emb.emb ----
  for (int pi = 0; pi < 16; pi++) {
    int k0 = (pi >> 2) * 32 + q * 8 + (pi & 3) * 2;
    half2_t a0 = {(_Float16)0.f, (_Float16)0.f};
    half2_t a1 = a0;
    const uint32_t* wr0 = &W1sL[k0 * 65];
    const uint32_t* wr1 = &W1sL[(k0 + 1) * 65];
    const uint32_t* ep = &encPL[m * 65];
#pragma unroll 8
    for (int c = 0; c < 64; c++) {
      half2_t e = __builtin_bit_cast(half2_t, ep[c]);
      a0 += __builtin_bit_cast(half2_t, wr0[c]) * e;
      a1 += __builtin_bit_cast(half2_t, wr1[c]) * e;
    }
#pragma unroll
    for (int c = 0; c < 8; c++) {
      half2_t e = __builtin_bit_cast(half2_t, embPL[m * 9 + c]);
      a0 += __builtin_bit_cast(half2_t, W1xL[k0 * 29 + 3 + c]) * e;       // cols 134..149
      a1 += __builtin_bit_cast(half2_t, W1xL[(k0 + 1) * 29 + 3 + c]) * e;
    }
    float e0 = b1[k0] + (float)a0.x + (float)a0.y;
    float e1 = b1[k0 + 1] + (float)a1.x + (float)a1.y;
    encdL[tid * 17 + pi] = pack2f(e0, e1);
  }

  // ---- per-lane resident weights ----
  uint4 Bf[2][4];
  const uint4* w2u4 = (const uint4*)w2p;
#pragma unroll
  for (int tt = 0; tt < 2; tt++) {
    int n = w * 32 + tt * 16 + m;
#pragma unroll
    for (int f = 0; f < 4; f++) Bf[tt][f] = w2u4[n * 16 + f * 4 + q];
  }
  const float w3v0 = W3[w * 32 + m], w3v1 = W3[w * 32 + 16 + m];
  const float b2v0 = b2[w * 32 + m], b2v1 = b2[w * 32 + 16 + m];
  const float b3v = b3[0];

  uint32_t w1yP[16];
#pragma unroll
  for (int pi = 0; pi < 16; pi++) {
    int k0 = (pi >> 2) * 32 + q * 8 + (pi & 3) * 2;
    uint32_t ua = W1xL[k0 * 29 + 11];         // halfs: col150(lo), col151(hi)
    uint32_t ub = W1xL[(k0 + 1) * 29 + 11];
    w1yP[pi] = (ua >> 16) | (ub & 0xFFFF0000u);
  }

  float prev_y = y0[bbase + m];
  float noi[8];
#pragma unroll
  for (int s = 0; s < 8; s++) noi[s] = noise[s * 1024 + bbase + m];
  __syncthreads();

  int buf = 0;
  for (int s = 0; s < 8; s++) {
    // base pairs for this AR step
    float xf[6];
#pragma unroll
    for (int i = 0; i < 6; i++) xf[i] = xfut[((bbase + m) * 8 + s) * 6 + i];
    uint32_t bph[16];
#pragma unroll
    for (int pi = 0; pi < 16; pi++) {
      int k0 = (pi >> 2) * 32 + q * 8 + (pi & 3) * 2;
      float2 ed = up2(encdL[tid * 17 + pi]);
      float e0 = ed.x, e1 = ed.y;
#pragma unroll
      for (int c = 0; c < 3; c++) {
        float2 w0v = up2(W1xL[k0 * 29 + c]);        // cols 128..133 (exo)
        float2 w1v = up2(W1xL[(k0 + 1) * 29 + c]);
        e0 += w0v.x * xf[2 * c] + w0v.y * xf[2 * c + 1];
        e1 += w1v.x * xf[2 * c] + w1v.y * xf[2 * c + 1];
      }
      e0 += up2(W1xL[k0 * 29 + 11]).x * prev_y;     // col 150
      e1 += up2(W1xL[(k0 + 1) * 29 + 11]).x * prev_y;
      e0 += (float)hprojL[s * 128 + k0];
      e1 += (float)hprojL[s * 128 + k0 + 1];
      bph[pi] = pack2f(e0, e1);
    }

    float y = noi[s];
    // preload t=99 tproj/cc and fold into bt = bph + tproj
    uint32_t bt[16];
    {
      const uint4* tb = (const uint4*)(tprojL + 99 * 128 + q * 8);
      uint4 t0 = tb[0], t1 = tb[4], t2 = tb[8], t3 = tb[12];
      bt[0] = pk_add(bph[0], t0.x);  bt[1] = pk_add(bph[1], t0.y);
      bt[2] = pk_add(bph[2], t0.z);  bt[3] = pk_add(bph[3], t0.w);
      bt[4] = pk_add(bph[4], t1.x);  bt[5] = pk_add(bph[5], t1.y);
      bt[6] = pk_add(bph[6], t1.z);  bt[7] = pk_add(bph[7], t1.w);
      bt[8] = pk_add(bph[8], t2.x);  bt[9] = pk_add(bph[9], t2.y);
      bt[10] = pk_add(bph[10], t2.z); bt[11] = pk_add(bph[11], t2.w);
      bt[12] = pk_add(bph[12], t3.x); bt[13] = pk_add(bph[13], t3.y);
      bt[14] = pk_add(bph[14], t3.z); bt[15] = pk_add(bph[15], t3.w);
    }
    float2 ccv = ccL[99];

    for (int t = 99; t >= 0; t--) {
      // ---- critical: y -> h1 (A frag) -> MFMA (2-deep) ----
      uint32_t yP = cvtpk(y);
      v4f c0a = {0.f, 0.f, 0.f, 0.f}, c0b = c0a, c1a = c0a, c1b = c0a;
#pragma unroll
      for (int f = 0; f < 4; f++) {
        uint4 au;
        au.x = pk_relufma(w1yP[4 * f + 0], yP, bt[4 * f + 0]);
        au.y = pk_relufma(w1yP[4 * f + 1], yP, bt[4 * f + 1]);
        au.z = pk_relufma(w1yP[4 * f + 2], yP, bt[4 * f + 2]);
        au.w = pk_relufma(w1yP[4 * f + 3], yP, bt[4 * f + 3]);
        v8h A = __builtin_bit_cast(v8h, au);
        if (f & 1) {
          c0b = __builtin_amdgcn_mfma_f32_16x16x32_f16(A, __builtin_bit_cast(v8h, Bf[0][f]), c0b, 0, 0, 0);
          c1b = __builtin_amdgcn_mfma_f32_16x16x32_f16(A, __builtin_bit_cast(v8h, Bf[1][f]), c1b, 0, 0, 0);
        } else {
          c0a = __builtin_amdgcn_mfma_f32_16x16x32_f16(A, __builtin_bit_cast(v8h, Bf[0][f]), c0a, 0, 0, 0);
          c1a = __builtin_amdgcn_mfma_f32_16x16x32_f16(A, __builtin_bit_cast(v8h, Bf[1][f]), c1a, 0, 0, 0);
        }
      }
      // ---- prefetch next step's tproj/cc (off critical path) ----
      const int tn = (t > 0) ? t - 1 : 0;
      const uint4* tb = (const uint4*)(tprojL + tn * 128 + q * 8);
      uint4 t0 = tb[0], t1 = tb[4], t2 = tb[8], t3 = tb[12];
      float2 ccn = ccL[tn];
      // ---- epilogue ----
      v4f c0 = c0a + c0b, c1 = c1a + c1b;
      float pr[4];
#pragma unroll
      for (int r = 0; r < 4; r++) {
        pr[r] = fmaxf(c0[r] + b2v0, 0.f) * w3v0 + fmaxf(c1[r] + b2v1, 0.f) * w3v1;
        pr[r] = rowsum16(pr[r]);
      }
      if ((l & 15) == 15)
        *(float4*)&partL[buf][w][q * 4] = make_float4(pr[0], pr[1], pr[2], pr[3]);
      // fold tproj[tn] into btn while the barrier settles
      uint32_t btn[16];
      btn[0] = pk_add(bph[0], t0.x);  btn[1] = pk_add(bph[1], t0.y);
      btn[2] = pk_add(bph[2], t0.z);  btn[3] = pk_add(bph[3], t0.w);
      btn[4] = pk_add(bph[4], t1.x);  btn[5] = pk_add(bph[5], t1.y);
      btn[6] = pk_add(bph[6], t1.z);  btn[7] = pk_add(bph[7], t1.w);
      btn[8] = pk_add(bph[8], t2.x);  btn[9] = pk_add(bph[9], t2.y);
      btn[10] = pk_add(bph[10], t2.z); btn[11] = pk_add(bph[11], t2.w);
      btn[12] = pk_add(bph[12], t3.x); btn[13] = pk_add(bph[13], t3.y);
      btn[14] = pk_add(bph[14], t3.z); btn[15] = pk_add(bph[15], t3.w);
      __syncthreads();
      float eps = b3v + ((partL[buf][0][m] + partL[buf][1][m]) +
                         (partL[buf][2][m] + partL[buf][3][m]));
      y = (y - ccv.x * eps) * ccv.y;
      ccv = ccn;
#pragma unroll
      for (int pi = 0; pi < 16; pi++) bt[pi] = btn[pi];
      buf ^= 1;
    }
    if (w == 0 && l < 16) out[(bbase + l) * 8 + s] = y;
    prev_y = y;
  }
}

// ---------------------------------------------------------------------------
extern "C" void kernel_launch(void* const* d_in, const int* in_sizes, int n_in,
                              void* d_out, int out_size, void* d_ws, size_t ws_size,
                              hipStream_t stream) {
  const float* x_hist    = (const float*)d_in[0];
  const float* x_future  = (const float*)d_in[1];
  const float* y0        = (const float*)d_in[2];
  const int*   turb_idx  = (const int*)d_in[3];
  const float* init_noise = (const float*)d_in[5];
  const float* turb_emb  = (const float*)d_in[6];
  const float* W_ih0     = (const float*)d_in[7];
  const float* W_hh0     = (const float*)d_in[8];
  const float* b_ih0     = (const float*)d_in[9];
  const float* b_hh0     = (const float*)d_in[10];
  const float* W_ih1     = (const float*)d_in[11];
  const float* W_hh1     = (const float*)d_in[12];
  const float* b_ih1     = (const float*)d_in[13];
  const float* b_hh1     = (const float*)d_in[14];
  const float* W1        = (const float*)d_in[15];
  const float* b1        = (const float*)d_in[16];
  const float* W2        = (const float*)d_in[17];
  const float* b2        = (const float*)d_in[18];
  const float* W3        = (const float*)d_in[19];
  const float* b3        = (const float*)d_in[20];

  char* ws = (char*)d_ws;
  uint32_t* xh16 = (uint32_t*)(ws + OFF_XH);
  uint32_t* w0p  = (uint32_t*)(ws + OFF_W0);
  float*    bs0  = (float*)(ws + OFF_BS0);
  uint32_t* w1p  = (uint32_t*)(ws + OFF_W1L);
  float*    bs1  = (float*)(ws + OFF_BS1);
  uint32_t* w2p  = (uint32_t*)(ws + OFF_W2P);
  float*    encf = (float*)(ws + OFF_ENC);
  __half*   ys0h = (__half*)(ws + OFF_YS0);

  k_prep_xh<<<4608, 256, 0, stream>>>(x_hist, turb_idx, turb_emb, xh16);
  k_prep_w<<<452, 256, 0, stream>>>(W_ih0, W_hh0, b_ih0, b_hh0,
                                    W_ih1, W_hh1, b_ih1, b_hh1,
                                    W2, w0p, w1p, w2p, bs0, bs1);
  k_lstm0<<<64, 512, 0, stream>>>(xh16, w0p, bs0, ys0h);
  k_lstm1<<<64, 512, 0, stream>>>((const uint32_t*)ys0h, w1p, bs1, encf);
  k_diff<<<64, 256, 0, stream>>>(x_future, y0, turb_idx, init_noise, turb_emb,
                                 W1, b1, b2, W3, b3, w2p, encf, (float*)d_out);
}